// Round 8
// baseline (1305.639 us; speedup 1.0000x reference)
//
#include <hip/hip_runtime.h>
#include <cstdio>
#include <cstdint>

typedef __bf16 bf16_t;
typedef __bf16 bf16x8 __attribute__((ext_vector_type(8)));
typedef __bf16 bf16x4 __attribute__((ext_vector_type(4)));
typedef float  f32x4  __attribute__((ext_vector_type(4)));

// problem dims
#define B_ROWS 8192
#define GEN    5000
#define GENP   5120   // padded K for gemm1 / N for merger (mult of 256, 64)
#define H1     4128
#define H1P    4224   // mult of 128 and 64; gemm1 N split as 4096 (256^2) + 128 (tail)
#define H2     2064
#define LT     1032
#define NMOD   129    // pathway modules (incl. aux)

// ---------------- async global->LDS helper ----------------
__device__ __forceinline__ void load_lds16(const bf16_t* g, bf16_t* l) {
  __builtin_amdgcn_global_load_lds((__attribute__((address_space(1))) void*)g,
                                   (__attribute__((address_space(3))) void*)l,
                                   16, 0, 0);
}

__device__ __forceinline__ int xcd_swizzle(int wg, int nwg) {
  const int q = nwg >> 3, r8 = nwg & 7;
  const int xcd = wg & 7, sidx = wg >> 3;
  return (xcd < r8 ? xcd * (q + 1) : r8 * (q + 1) + (xcd - r8) * q) + sidx;
}

// =======================================================================
// 256x256 8-wave 8-phase GEMM, counted vmcnt, kk-outer MFMA (dep dist 8).
// BK=64, 2 K-tiles/iter (T->buf0, T+1->buf1). Staging (16 loads/iter):
//   P3: B[T+2]g0,g1  P4: B[T+2]g2,g3  P5: A[T+2]g0,g2  P6: A[T+2]g1,g3
//   P7: B[T+3]g0,g1  P8: B[T+3]g2,g3 + A[T+3]g0..g3  (A fully staged @P8)
// Ledger (oldest-first) @P4-wait: prevP7(2)+prevP8(6)+P3(2)+P4(2)=12;
//   vmcnt(4) retires 8 = thru A[T+1]g3 (issued 4+ phases back). @P8-wait:
//   P3..P8 = 16; vmcnt(8) retires thru P6 = A[T+2],B[T+2]. Buffer-free:
//   B-buf0 (P3/4) after B[T] last read P2; A-buf0 (P5/6) after A[T] @P3;
//   B-buf1 (P7/8) after B[T+1] @P6; A-buf1 (P8) after A[T+1] @P7. pf2 ==
//   (T+2<NT) guards all prefetch (NT even -> pf2 implies T+3<NT).
// MODE 0: bf16 C (ld Npad) + per-column sum/sumsq atomics.
// MODE 1: f32 C, row stride Cld, col bound Nvalid.
// =======================================================================
template<int MODE>
__global__ __launch_bounds__(512, 2)
void gemm256(const bf16_t* __restrict__ A, const bf16_t* __restrict__ Bm,
             int K, bf16_t* __restrict__ Cb, int Npad,
             float* __restrict__ sum, float* __restrict__ sq,
             float* __restrict__ Cf, int Nvalid, int Cld)
{
  __shared__ bf16_t As[2][256 * 64];
  __shared__ bf16_t Bs[2][256 * 64];
  const int tid  = threadIdx.x;
  const int wave = tid >> 6;
  const int lane = tid & 63;

  int wg = xcd_swizzle((int)blockIdx.x + (int)blockIdx.y * gridDim.x,
                       gridDim.x * gridDim.y);
  const int brow = (wg / gridDim.x) * 256;
  const int bcol = (wg % gridDim.x) * 256;

  const int wm = wave >> 2;      // 0..1 -> 128-row half
  const int wn = wave & 3;       // 0..3 -> 64-col slice

  // staging: 8 threads per 64-elem row, 16B granule, XOR-swizzled source
  const int rr = tid >> 3;                        // 0..63
  const int cc = (((tid & 7) ^ (rr & 7)) << 3);
  const bf16_t* ga = A  + (size_t)(brow + rr) * K + cc;
  const bf16_t* gb = Bm + (size_t)(bcol + rr) * K + cc;

  auto stA = [&](int d, int i, long ko) {
    load_lds16(ga + (size_t)(i * 64) * K + ko, &As[d][(i * 64 + wave * 8) * 64]);
  };
  auto stB = [&](int d, int i, long ko) {
    load_lds16(gb + (size_t)(i * 64) * K + ko, &Bs[d][(i * 64 + wave * 8) * 64]);
  };

  f32x4 acc[8][4] = {};
  bf16x8 alo[4][2], ahi[4][2], blo[2][2], bhi[2][2];

  const int lr  = lane & 15;
  const int hi  = lane >> 4;
  const int rsw = lr & 7;
  const int arb = wm * 128 + lr;  // A row base (+ MB*64 + mf*16)
  const int bcb = wn * 64 + lr;   // B col base (+ nf*16)

#define RD_A(DST, MB, dd)                                                     \
  _Pragma("unroll") for (int mf = 0; mf < 4; ++mf)                            \
  _Pragma("unroll") for (int kk = 0; kk < 2; ++kk)                            \
    DST[mf][kk] = *(const bf16x8*)&As[dd][(arb + (MB) * 64 + mf * 16) * 64 +  \
                                          (((kk * 4 + hi) ^ rsw) << 3)];
#define RD_B(DST, NB, dd)                                                     \
  _Pragma("unroll") for (int nf = 0; nf < 2; ++nf)                            \
  _Pragma("unroll") for (int kk = 0; kk < 2; ++kk)                            \
    DST[nf][kk] = *(const bf16x8*)&Bs[dd][(bcb + (NB) * 16 + nf * 16) * 64 +  \
                                          (((kk * 4 + hi) ^ rsw) << 3)];
// kk OUTERMOST: 8 independent accs between dependent uses (hides MFMA latency)
#define MFMA_Q(AF, BF, MB, NB)                                                \
  _Pragma("unroll") for (int kk = 0; kk < 2; ++kk)                            \
  _Pragma("unroll") for (int mf = 0; mf < 4; ++mf)                            \
  _Pragma("unroll") for (int nf = 0; nf < 2; ++nf)                            \
    acc[(MB) + mf][(NB) + nf] = __builtin_amdgcn_mfma_f32_16x16x32_bf16(      \
        AF[mf][kk], BF[nf][kk], acc[(MB) + mf][(NB) + nf], 0, 0, 0);

#define LGKM0  asm volatile("s_waitcnt lgkmcnt(0)" ::: "memory")
#define LGKM8  asm volatile("s_waitcnt lgkmcnt(8)" ::: "memory")
#define VMW(N) asm volatile("s_waitcnt vmcnt(" #N ")" ::: "memory")
#define BARR   __builtin_amdgcn_s_barrier()
#define PRIO1  __builtin_amdgcn_s_setprio(1)
#define PRIO0  __builtin_amdgcn_s_setprio(0)

  const int NT = K >> 6;          // even by construction

  // prologue: A[0],B[0]->buf0 complete; B[1],A[1]->buf1 in flight (8)
  stA(0, 0, 0); stA(0, 1, 0); stA(0, 2, 0); stA(0, 3, 0);
  stB(0, 0, 0); stB(0, 1, 0); stB(0, 2, 0); stB(0, 3, 0);
  stB(1, 0, 64); stB(1, 1, 64); stB(1, 2, 64); stB(1, 3, 64);
  stA(1, 0, 64); stA(1, 1, 64); stA(1, 2, 64); stA(1, 3, 64);
  VMW(8);                        // completes A[0],B[0]; leaves B[1](4)+A[1](4)
  BARR;

  for (int it = 0; it < (NT >> 1); ++it) {
    const int  T   = it * 2;
    const long k2  = (long)(T + 2) * 64;
    const long k3  = (long)(T + 3) * 64;
    const bool pf2 = (T + 2 < NT);   // NT even -> implies T+3 < NT

    // P1: Q(lo,lo) of T
    RD_A(alo, 0, 0); RD_B(blo, 0, 0);
    LGKM8;
    BARR; LGKM0; PRIO1; MFMA_Q(alo, blo, 0, 0); PRIO0; BARR;

    // P2: Q(lo,hi)
    RD_B(bhi, 2, 0);
    BARR; LGKM0; PRIO1; MFMA_Q(alo, bhi, 0, 2); PRIO0; BARR;

    // P3: Q(hi,hi); stage B[T+2]g0,g1 -> buf0 (B[T] retired @P2)
    RD_A(ahi, 1, 0);
    if (pf2) { stB(0, 0, k2); stB(0, 1, k2); }
    BARR; LGKM0; PRIO1; MFMA_Q(ahi, bhi, 4, 2); PRIO0; BARR;

    // P4: Q(hi,lo); stage B[T+2]g2,g3; wait -> A[T+1] ready (issued prevP8)
    if (pf2) { stB(0, 2, k2); stB(0, 3, k2); }
    PRIO1; MFMA_Q(ahi, blo, 4, 0); PRIO0;
    if (pf2) { VMW(4); } else { VMW(0); }
    BARR;

    // P5: Q(lo,lo) of T+1; stage A[T+2]g0,g2 -> buf0 (A[T] retired @P3)
    RD_A(alo, 0, 1); RD_B(blo, 0, 1);
    if (pf2) { stA(0, 0, k2); stA(0, 2, k2); }
    LGKM8;
    BARR; LGKM0; PRIO1; MFMA_Q(alo, blo, 0, 0); PRIO0; BARR;

    // P6: Q(lo,hi); stage A[T+2]g1,g3
    RD_B(bhi, 2, 1);
    if (pf2) { stA(0, 1, k2); stA(0, 3, k2); }
    BARR; LGKM0; PRIO1; MFMA_Q(alo, bhi, 0, 2); PRIO0; BARR;

    // P7: Q(hi,hi); stage B[T+3]g0,g1 -> buf1 (B[T+1] retired @P6)
    RD_A(ahi, 1, 1);
    if (pf2) { stB(1, 0, k3); stB(1, 1, k3); }
    BARR; LGKM0; PRIO1; MFMA_Q(ahi, bhi, 4, 2); PRIO0; BARR;

    // P8: Q(hi,lo); stage B[T+3]g2,g3 then A[T+3] FULL (A[T+1] retired @P7)
    if (pf2) { stB(1, 2, k3); stB(1, 3, k3);
               stA(1, 0, k3); stA(1, 1, k3); stA(1, 2, k3); stA(1, 3, k3); }
    PRIO1; MFMA_Q(ahi, blo, 4, 0); PRIO0;
    if (pf2) { VMW(8); BARR; }       // retires thru P6 (A[T+2],B[T+2])
  }

  // epilogue: C/D layout col=lane&15, row=(lane>>4)*4+reg
  if (MODE == 0) {
#pragma unroll
    for (int nf = 0; nf < 4; ++nf) {
      const int colg = bcol + wn * 64 + nf * 16 + lr;
      float s = 0.f, s2 = 0.f;
#pragma unroll
      for (int mf = 0; mf < 8; ++mf) {
        const int rowg = brow + wm * 128 + mf * 16 + hi * 4;
#pragma unroll
        for (int r = 0; r < 4; ++r) {
          float v = acc[mf][nf][r];
          s += v; s2 += v * v;
          Cb[(size_t)(rowg + r) * Npad + colg] = (bf16_t)v;
        }
      }
      s  += __shfl_xor(s, 16, 64);  s  += __shfl_xor(s, 32, 64);
      s2 += __shfl_xor(s2, 16, 64); s2 += __shfl_xor(s2, 32, 64);
      if (lane < 16) {
        atomicAdd(&sum[colg], s);
        atomicAdd(&sq[colg], s2);
      }
    }
  } else {
#pragma unroll
    for (int nf = 0; nf < 4; ++nf) {
      const int colg = bcol + wn * 64 + nf * 16 + lr;
      if (colg < Nvalid) {
#pragma unroll
        for (int mf = 0; mf < 8; ++mf) {
          const int rowg = brow + wm * 128 + mf * 16 + hi * 4;
#pragma unroll
          for (int r = 0; r < 4; ++r)
            Cf[(size_t)(rowg + r) * Cld + colg] = acc[mf][nf][r];
        }
      }
    }
  }
#undef RD_A
#undef RD_B
#undef MFMA_Q
#undef LGKM0
#undef LGKM8
#undef VMW
#undef BARR
#undef PRIO1
#undef PRIO0
}

// =======================================================================
// 128x128 4-wave GEMM (round-2 structure) — tail strips
// =======================================================================
template<int MODE>
__global__ __launch_bounds__(256, 2)
void gemm_bt(const bf16_t* __restrict__ A, const bf16_t* __restrict__ Bm,
             int K, bf16_t* __restrict__ Cb, int Npad,
             float* __restrict__ sum, float* __restrict__ sq,
             float* __restrict__ Cf, int Nvalid, int Cld)
{
  __shared__ bf16_t As[128 * 64];
  __shared__ bf16_t Bs[128 * 64];
  const int tid  = threadIdx.x;
  const int wave = tid >> 6;
  const int lane = tid & 63;

  int wg = xcd_swizzle((int)blockIdx.x + (int)blockIdx.y * gridDim.x,
                       gridDim.x * gridDim.y);
  const int brow = (wg / gridDim.x) * 128;
  const int bcol = (wg % gridDim.x) * 128;

  const int wrow = (wave >> 1) * 64;
  const int wcol = (wave & 1) * 64;

  const int rr  = tid >> 3;                         // 0..31
  const int cc  = (((tid & 7) ^ (rr & 7)) << 3);    // swizzled 8-elem granule

  const bf16_t* ga[4];
  const bf16_t* gb[4];
#pragma unroll
  for (int i = 0; i < 4; ++i) {
    ga[i] = A  + (size_t)(brow + i * 32 + rr) * K + cc;
    gb[i] = Bm + (size_t)(bcol + i * 32 + rr) * K + cc;
  }
  bf16_t* lab = As + wave * 512;
  bf16_t* lbb = Bs + wave * 512;

  f32x4 acc[4][4] = {};

  const int lr  = lane & 15;
  const int g0  = lane >> 4;
  const int rsw = lr & 7;

  for (int kt = 0; kt < K; kt += 64) {
#pragma unroll
    for (int i = 0; i < 4; ++i) {
      load_lds16(ga[i] + kt, lab + i * 2048);
      load_lds16(gb[i] + kt, lbb + i * 2048);
    }
    __syncthreads();
#pragma unroll
    for (int kk = 0; kk < 2; ++kk) {
      const int swz = (((kk * 4 + g0) ^ rsw) << 3);
      bf16x8 af[4], bfr[4];
#pragma unroll
      for (int mi = 0; mi < 4; ++mi)
        af[mi] = *(const bf16x8*)(As + (wrow + mi * 16 + lr) * 64 + swz);
#pragma unroll
      for (int ni = 0; ni < 4; ++ni)
        bfr[ni] = *(const bf16x8*)(Bs + (wcol + ni * 16 + lr) * 64 + swz);
#pragma unroll
      for (int mi = 0; mi < 4; ++mi)
#pragma unroll
        for (int ni = 0; ni < 4; ++ni)
          acc[mi][ni] = __builtin_amdgcn_mfma_f32_16x16x32_bf16(af[mi], bfr[ni], acc[mi][ni], 0, 0, 0);
    }
    __syncthreads();
  }

  const int lcol = lane & 15;
  const int lrow = (lane >> 4) * 4;
  if (MODE == 0) {
#pragma unroll
    for (int ni = 0; ni < 4; ++ni) {
      const int colg = bcol + wcol + ni * 16 + lcol;
      float s = 0.f, s2 = 0.f;
#pragma unroll
      for (int mi = 0; mi < 4; ++mi) {
        const int rowg = brow + wrow + mi * 16 + lrow;
#pragma unroll
        for (int r = 0; r < 4; ++r) {
          float v = acc[mi][ni][r];
          s += v; s2 += v * v;
          Cb[(size_t)(rowg + r) * Npad + colg] = (bf16_t)v;
        }
      }
      s  += __shfl_xor(s, 16, 64);  s  += __shfl_xor(s, 32, 64);
      s2 += __shfl_xor(s2, 16, 64); s2 += __shfl_xor(s2, 32, 64);
      if (lane < 16) {
        atomicAdd(&sum[colg], s);
        atomicAdd(&sq[colg], s2);
      }
    }
  } else {
#pragma unroll
    for (int ni = 0; ni < 4; ++ni) {
      const int colg = bcol + wcol + ni * 16 + lcol;
      if (colg < Nvalid) {
#pragma unroll
        for (int mi = 0; mi < 4; ++mi) {
          const int rowg = brow + wrow + mi * 16 + lrow;
#pragma unroll
          for (int r = 0; r < 4; ++r)
            Cf[(size_t)(rowg + r) * Cld + colg] = acc[mi][ni][r];
        }
      }
    }
  }
}

// ---------------- prep: out[npad][kpad] = bf16(W*mask), zero-padded ----------------
__global__ void k_prep(const float* __restrict__ W, const float* __restrict__ Mk,
                       bf16_t* __restrict__ out, int N, int K, int Npad, int Kpad)
{
  const int  kg    = Kpad >> 3;
  const long total = (long)Npad * kg;
  for (long idx = (long)blockIdx.x * blockDim.x + threadIdx.x; idx < total;
       idx += (long)gridDim.x * blockDim.x) {
    const int n = (int)(idx / kg);
    const int c = (int)(idx % kg) * 8;
    bf16x8 o;
#pragma unroll
    for (int j = 0; j < 8; ++j) o[j] = (bf16_t)0.f;
    if (n < N && c < K) {               // K % 8 == 0 for all inputs
      const f32x4* w4 = (const f32x4*)(W + (size_t)n * K + c);
      f32x4 a = w4[0], b = w4[1];
      if (Mk) {
        const f32x4* m4 = (const f32x4*)(Mk + (size_t)n * K + c);
        f32x4 ma = m4[0], mb = m4[1];
        a *= ma; b *= mb;
      }
#pragma unroll
      for (int j = 0; j < 4; ++j) { o[j] = (bf16_t)a[j]; o[4 + j] = (bf16_t)b[j]; }
    }
    *(bf16x8*)(out + (size_t)idx * 8) = o;
  }
}

// ---------------- BN finalize: sum->scale, sq->shift ----------------
__global__ void k_finalize(float* __restrict__ sum, float* __restrict__ sq,
                           const float* __restrict__ g, const float* __restrict__ be,
                           int Nvalid, int Npad)
{
  const int c = blockIdx.x * blockDim.x + threadIdx.x;
  if (c >= Npad) return;
  float sc = 0.f, sh = 0.f;
  if (c < Nvalid) {
    const float invM = 1.0f / 8192.0f;
    float mean = sum[c] * invM;
    float var  = sq[c] * invM - mean * mean;
    sc = g[c] * rsqrtf(var + 1e-3f);
    sh = be[c] - mean * sc;
  }
  sum[c] = sc; sq[c] = sh;
}

// ---------------- BN apply (+optional ELU, optional f32 out) ----------------
__global__ void k_bn_elu(const bf16_t* __restrict__ pre, const float* __restrict__ sc,
                         const float* __restrict__ sh, bf16_t* __restrict__ outb,
                         float* __restrict__ outf, int Nvalid, int Npad, int elu)
{
  const int  ng    = Npad >> 3;
  const long total = (long)B_ROWS * ng;
  for (long idx = (long)blockIdx.x * blockDim.x + threadIdx.x; idx < total;
       idx += (long)gridDim.x * blockDim.x) {
    const int r = (int)(idx / ng);
    const int c = (int)(idx % ng) * 8;
    bf16x8 o;
#pragma unroll
    for (int j = 0; j < 8; ++j) o[j] = (bf16_t)0.f;
    if (c < Nvalid) {                   // Nvalid % 8 == 0 -> group fully valid
      bf16x8 x = *(const bf16x8*)(pre + (size_t)r * Npad + c);
      f32x4 y0, y1;
#pragma unroll
      for (int j = 0; j < 8; ++j) {
        float v = (float)x[j] * sc[c + j] + sh[c + j];
        if (elu) v = v > 0.f ? v : expm1f(v);
        if (j < 4) y0[j] = v; else y1[j - 4] = v;
        o[j] = (bf16_t)v;
      }
      if (outf) {
        float* p = outf + (size_t)r * Nvalid + c;
        *(f32x4*)p       = y0;
        *(f32x4*)(p + 4) = y1;
      }
    }
    *(bf16x8*)(outb + (size_t)r * Npad + c) = o;
  }
}

// =======================================================================
// k_enc2: block-diagonal encoder L2, fused BN1+ELU (round-6, verified)
// =======================================================================
__global__ __launch_bounds__(256)
void k_enc2(const bf16_t* __restrict__ hpre,
            const float* __restrict__ sc1, const float* __restrict__ sh1,
            const float* __restrict__ W2,
            bf16_t* __restrict__ pp,
            float* __restrict__ s2, float* __restrict__ q2)
{
  __shared__ float ws2[16][32];
  __shared__ float lsc[32], lsh[32];
  __shared__ float dbuf[256][17];
  __shared__ float part[2][4][16];
  const int m = blockIdx.x;
  const int t = threadIdx.x;
  const int b = blockIdx.y * 256 + t;

  for (int i = t; i < 512; i += 256) {
    const int r = i >> 5, j = i & 31;
    const int grow = (r < 8) ? (m * 8 + r) : (LT + m * 8 + (r - 8));
    ws2[r][j] = W2[(size_t)grow * H1 + m * 32 + j];
  }
  if (t < 32) lsc[t] = sc1[m * 32 + t];
  else if (t < 64) lsh[t - 32] = sh1[m * 32 + (t - 32)];
  __syncthreads();

  float h[32];
  const bf16_t* hp = hpre + (size_t)b * H1P + m * 32;
#pragma unroll
  for (int v = 0; v < 4; ++v) {
    bf16x8 x = *(const bf16x8*)(hp + v * 8);
#pragma unroll
    for (int j = 0; j < 8; ++j) {
      float val = (float)x[j] * lsc[v * 8 + j] + lsh[v * 8 + j];
      h[v * 8 + j] = val > 0.f ? val : expm1f(val);
    }
  }

  float p[16];
#pragma unroll
  for (int i = 0; i < 16; ++i) {
    float a = 0.f;
#pragma unroll
    for (int jb = 0; jb < 8; ++jb) {
      f32x4 w = *(const f32x4*)&ws2[i][jb * 4];
      a = fmaf(w[0], h[jb * 4 + 0], a);
      a = fmaf(w[1], h[jb * 4 + 1], a);
      a = fmaf(w[2], h[jb * 4 + 2], a);
      a = fmaf(w[3], h[jb * 4 + 3], a);
    }
    p[i] = a;
  }

  bf16x8 o0, o1;
#pragma unroll
  for (int i = 0; i < 8; ++i) { o0[i] = (bf16_t)p[i]; o1[i] = (bf16_t)p[8 + i]; }
  bf16_t* pw = pp + ((size_t)m * B_ROWS + b) * 16;
  *(bf16x8*)pw = o0; *(bf16x8*)(pw + 8) = o1;

  // stats
#pragma unroll
  for (int i = 0; i < 16; ++i) dbuf[t][i] = p[i];
  __syncthreads();
  {
    const int col = t & 15, sl = t >> 4;   // 16 slices of 16 rows
    float s = 0.f, q = 0.f;
#pragma unroll
    for (int r = 0; r < 16; ++r) {
      float v = dbuf[sl * 16 + r][col];
      s += v; q += v * v;
    }
    s += __shfl_xor(s, 16, 64); s += __shfl_xor(s, 32, 64);
    q += __shfl_xor(q, 16, 64); q += __shfl_xor(q, 32, 64);
    const int w = t >> 6;
    if ((t & 63) < 16) { part[0][w][col] = s; part[1][w][col] = q; }
    __syncthreads();
    if (t < 16) {
      float ss = part[0][0][t] + part[0][1][t] + part[0][2][t] + part[0][3][t];
      float qq = part[1][0][t] + part[1][1][t] + part[1][2][t] + part[1][3][t];
      const int gc = (t < 8) ? (m * 8 + t) : (LT + m * 8 + (t - 8));
      atomicAdd(&s2[gc], ss);
      atomicAdd(&q2[gc], qq);
    }
  }
}

// =======================================================================
// k_dec: fused BN2 + reparametrize + block-diagonal decoder L1 (round-6)
// =======================================================================
__global__ __launch_bounds__(256)
void k_dec(const bf16_t* __restrict__ pp,
           const float* __restrict__ sc2, const float* __restrict__ sh2,
           const float* __restrict__ eps, const float* __restrict__ Wd,
           float* __restrict__ o_z, float* __restrict__ o_mu, float* __restrict__ o_lv,
           bf16_t* __restrict__ dpre,
           float* __restrict__ sd, float* __restrict__ qd)
{
  __shared__ float wd[32][8];
  __shared__ float lsc[16], lsh[16];
  __shared__ float dbuf[256][33];
  __shared__ float part[2][4][32];
  const int m = blockIdx.x;
  const int t = threadIdx.x;
  const int b = blockIdx.y * 256 + t;

  {
    const int j = t >> 3, l = t & 7;
    wd[j][l] = Wd[(size_t)(m * 32 + j) * LT + m * 8 + l];
  }
  if (t < 16) {
    const int gc = (t < 8) ? (m * 8 + t) : (LT + m * 8 + (t - 8));
    lsc[t] = sc2[gc]; lsh[t] = sh2[gc];
  }
  __syncthreads();

  const bf16_t* pr = pp + ((size_t)m * B_ROWS + b) * 16;
  bf16x8 pmv = *(const bf16x8*)pr;
  bf16x8 plv = *(const bf16x8*)(pr + 8);
  f32x4 e0 = *(const f32x4*)(eps + (size_t)b * LT + m * 8);
  f32x4 e1 = *(const f32x4*)(eps + (size_t)b * LT + m * 8 + 4);

  float z[8];
  f32x4 mu0, mu1, lv0, lv1, z0, z1;
#pragma unroll
  for (int l = 0; l < 8; ++l) {
    float muv = (float)pmv[l] * lsc[l] + lsh[l];
    float lvv = (float)plv[l] * lsc[8 + l] + lsh[8 + l];
    float ee  = (l < 4) ? e0[l] : e1[l - 4];
    float zz  = fmaf(expf(lvv * 0.5f), ee, muv);
    z[l] = zz;
    if (l < 4) { mu0[l] = muv; lv0[l] = lvv; z0[l] = zz; }
    else       { mu1[l-4] = muv; lv1[l-4] = lvv; z1[l-4] = zz; }
  }
  {
    const size_t o = (size_t)b * LT + m * 8;
    *(f32x4*)(o_z  + o) = z0; *(f32x4*)(o_z  + o + 4) = z1;
    *(f32x4*)(o_mu + o) = mu0; *(f32x4*)(o_mu + o + 4) = mu1;
    *(f32x4*)(o_lv + o) = lv0; *(f32x4*)(o_lv + o + 4) = lv1;
  }

  float d[32];
#pragma unroll
  for (int j = 0; j < 32; ++j) {
    f32x4 w0 = *(const f32x4*)&wd[j][0];
    f32x4 w1 = *(const f32x4*)&wd[j][4];
    float a = 0.f;
    a = fmaf(w0[0], z[0], a); a = fmaf(w0[1], z[1], a);
    a = fmaf(w0[2], z[2], a); a = fmaf(w0[3], z[3], a);
    a = fmaf(w1[0], z[4], a); a = fmaf(w1[1], z[5], a);
    a = fmaf(w1[2], z[6], a); a = fmaf(w1[3], z[7], a);
    d[j] = a;
  }
  {
    bf16_t* dw = dpre + (size_t)b * H1P + m * 32;
#pragma unroll
    for (int v = 0; v < 4; ++v) {
      bf16x8 o;
#pragma unroll
      for (int j = 0; j < 8; ++j) o[j] = (bf16_t)d[v * 8 + j];
      *(bf16x8*)(dw + v * 8) = o;
    }
  }

  // stats
#pragma unroll
  for (int j = 0; j < 32; ++j) dbuf[t][j] = d[j];
  __syncthreads();
  {
    const int col = t & 31, sl = t >> 5;   // 8 slices of 32 rows
    float s = 0.f, q = 0.f;
#pragma unroll
    for (int r = 0; r < 32; ++r) {
      float v = dbuf[sl * 32 + r][col];
      s += v; q += v * v;
    }
    s += __shfl_xor(s, 32, 64);
    q += __shfl_xor(q, 32, 64);
    const int w = t >> 6;
    if ((t & 63) < 32) { part[0][w][col] = s; part[1][w][col] = q; }
    __syncthreads();
    if (t < 32) {
      float ss = part[0][0][t] + part[0][1][t] + part[0][2][t] + part[0][3][t];
      float qq = part[1][0][t] + part[1][1][t] + part[1][2][t] + part[1][3][t];
      atomicAdd(&sd[m * 32 + t], ss);
      atomicAdd(&qd[m * 32 + t], qq);
    }
  }
}

// ---------------- host ----------------
extern "C" void kernel_launch(void* const* d_in, const int* in_sizes, int n_in,
                              void* d_out, int out_size, void* d_ws, size_t ws_size,
                              hipStream_t stream)
{
  const float* x     = (const float*)d_in[0];
  const float* eps   = (const float*)d_in[1];
  const float* mask1 = (const float*)d_in[2];
  // mask2 (d_in[3]) / maskd (d_in[4]): block-diagonal structure exploited directly
  const float* maskm = (const float*)d_in[5];
  const float* W1    = (const float*)d_in[6];
  // b1 (d_in[7]) cancels in BN (mean subtraction)
  const float* g1    = (const float*)d_in[8];
  const float* be1   = (const float*)d_in[9];
  const float* W2    = (const float*)d_in[10];
  // b2 (d_in[11]) cancels in BN
  const float* g2    = (const float*)d_in[12];
  const float* be2   = (const float*)d_in[13];
  const float* Wd    = (const float*)d_in[14];
  // bd (d_in[15]) cancels in BN
  const float* gd    = (const float*)d_in[16];
  const float* bed   = (const float*)d_in[17];
  const float* Wm    = (const float*)d_in[18];
  float* out = (float*)d_out;
  char*  ws  = (char*)d_ws;

  size_t off = 0;
  auto alloc = [&](size_t bytes) { size_t o = off; off += (bytes + 255) & ~(size_t)255; return o; };
  const size_t XBF  = alloc((size_t)B_ROWS * GENP * 2);   // x bf16; later mo bf16
  const size_t W1M  = alloc((size_t)H1P * GENP * 2);      // W1 masked; later pp
  const size_t WMM  = alloc((size_t)GENP * H1P * 2);      // Wm masked
  const size_t HPRE = alloc((size_t)B_ROWS * H1P * 2);    // h_pre; later d_pre
  const size_t STAT = alloc((size_t)(H1P + H2 + H1P) * 2 * sizeof(float));
  if (ws_size < off) {
    fprintf(stderr, "kernel_launch: workspace too small: need %zu have %zu\n", off, ws_size);
    return;
  }

  bf16_t* xb   = (bf16_t*)(ws + XBF);
  bf16_t* w1m  = (bf16_t*)(ws + W1M);
  bf16_t* wmm  = (bf16_t*)(ws + WMM);
  bf16_t* hpre = (bf16_t*)(ws + HPRE);
  bf16_t* pp   = (bf16_t*)(ws + W1M);   // alias: W1 masked dead after GEMM1
  bf16_t* dpre = (bf16_t*)(ws + HPRE);  // alias: h_pre dead after k_enc2
  bf16_t* mobf = (bf16_t*)(ws + XBF);   // alias: x bf16 dead after GEMM1

  float* s1 = (float*)(ws + STAT);
  float* q1 = s1 + H1P;
  float* s2 = q1 + H1P;
  float* q2 = s2 + H2;
  float* sd = q2 + H2;
  float* qd = sd + H1P;

  float* o_recon = out;
  float* o_z     = o_recon + (size_t)B_ROWS * GEN;
  float* o_mo    = o_z     + (size_t)B_ROWS * LT;
  float* o_mu    = o_mo    + (size_t)B_ROWS * H1;
  float* o_lv    = o_mu    + (size_t)B_ROWS * LT;

  hipMemsetAsync(ws + STAT, 0, (size_t)(H1P + H2 + H1P) * 2 * sizeof(float), stream);

  // prep: cast/mask to bf16, zero-padded
  k_prep<<<2048, 256, 0, stream>>>(x,  nullptr, xb,  B_ROWS, GEN, B_ROWS, GENP);
  k_prep<<<2048, 256, 0, stream>>>(W1, mask1,   w1m, H1,  GEN, H1P,  GENP);
  k_prep<<<2048, 256, 0, stream>>>(Wm, maskm,   wmm, GEN, H1,  GENP, H1P);

  // encoder L1: h_pre = x @ W1m^T (+ batch stats)
  // main: cols 0..4095 via 256^2 8-phase (512 blocks = 2 full CU generations)
  gemm256<0><<<dim3(4096 / 256, B_ROWS / 256), 512, 0, stream>>>(
      xb, w1m, GENP, hpre, H1P, s1, q1, nullptr, 0, 0);
  // tail: cols 4096..4223 via 128^2
  gemm_bt<0><<<dim3(1, B_ROWS / 128), 256, 0, stream>>>(
      xb, w1m + (size_t)4096 * GENP, GENP, hpre + 4096, H1P,
      s1 + 4096, q1 + 4096, nullptr, 0, 0);
  k_finalize<<<(H1P + 255) / 256, 256, 0, stream>>>(s1, q1, g1, be1, H1, H1P);

  // encoder L2 (block-diagonal, fused BN1+ELU) -> pp + stats2
  k_enc2<<<dim3(NMOD, B_ROWS / 256), 256, 0, stream>>>(hpre, s1, q1, W2, pp, s2, q2);
  k_finalize<<<(H2 + 255) / 256, 256, 0, stream>>>(s2, q2, g2, be2, H2, H2);

  // decoder L1 (block-diagonal, fused BN2 + reparam) -> dpre + stats_d + z/mu/lv
  k_dec<<<dim3(NMOD, B_ROWS / 256), 256, 0, stream>>>(pp, s2, q2, eps, Wd,
                                                      o_z, o_mu, o_lv, dpre, sd, qd);
  k_finalize<<<(H1P + 255) / 256, 256, 0, stream>>>(sd, qd, gd, bed, H1, H1P);

  // BN_d + ELU -> module_outputs (bf16 padded + f32 out)
  k_bn_elu<<<2048, 256, 0, stream>>>(dpre, sd, qd, mobf, o_mo, H1, H1P, 1);

  // merger: global_recon = mo @ Wmm^T (f32 out)
  // main: cols 0..4095 (512 blocks = 2 full generations)
  gemm256<1><<<dim3(4096 / 256, B_ROWS / 256), 512, 0, stream>>>(
      mobf, wmm, H1P, nullptr, 0, nullptr, nullptr, o_recon, GEN, GEN);
  // tail: cols 4096..4999 (bound 904) via 128^2, 512 blocks
  gemm_bt<1><<<dim3((GENP - 4096) / 128, B_ROWS / 128), 256, 0, stream>>>(
      mobf, wmm + (size_t)4096 * H1P, H1P, nullptr, 0, nullptr, nullptr,
      o_recon + 4096, GEN - 4096, GEN);
}

// Round 9
// 1242.639 us; speedup vs baseline: 1.0507x; 1.0507x over previous
//
#include <hip/hip_runtime.h>
#include <cstdio>
#include <cstdint>

typedef __bf16 bf16_t;
typedef __bf16 bf16x8 __attribute__((ext_vector_type(8)));
typedef __bf16 bf16x4 __attribute__((ext_vector_type(4)));
typedef float  f32x4  __attribute__((ext_vector_type(4)));

// problem dims
#define B_ROWS 8192
#define GEN    5000
#define GENP   5120   // padded K for gemm1 / N for merger (mult of 256, 64)
#define H1     4128
#define H1P    4224   // stride of hpre/dpre/mobf
#define H2     2064
#define LT     1032
#define NMOD   129    // pathway modules (incl. aux)

// ---------------- async global->LDS helper ----------------
__device__ __forceinline__ void load_lds16(const bf16_t* g, bf16_t* l) {
  __builtin_amdgcn_global_load_lds((__attribute__((address_space(1))) void*)g,
                                   (__attribute__((address_space(3))) void*)l,
                                   16, 0, 0);
}

__device__ __forceinline__ int xcd_swizzle(int wg, int nwg) {
  const int q = nwg >> 3, r8 = nwg & 7;
  const int xcd = wg & 7, sidx = wg >> 3;
  return (xcd < r8 ? xcd * (q + 1) : r8 * (q + 1) + (xcd - r8) * q) + sidx;
}

// =======================================================================
// 256x256 8-wave 8-phase GEMM, counted vmcnt, kk-outer MFMA (r8, 364us/944TF)
// MODE 0: bf16 C (ld Npad) + per-column sum/sumsq atomics.
// MODE 1: f32 C, row stride Cld, col bound Nvalid.
// =======================================================================
template<int MODE>
__global__ __launch_bounds__(512, 2)
void gemm256(const bf16_t* __restrict__ A, const bf16_t* __restrict__ Bm,
             int K, bf16_t* __restrict__ Cb, int Npad,
             float* __restrict__ sum, float* __restrict__ sq,
             float* __restrict__ Cf, int Nvalid, int Cld)
{
  __shared__ bf16_t As[2][256 * 64];
  __shared__ bf16_t Bs[2][256 * 64];
  const int tid  = threadIdx.x;
  const int wave = tid >> 6;
  const int lane = tid & 63;

  int wg = xcd_swizzle((int)blockIdx.x + (int)blockIdx.y * gridDim.x,
                       gridDim.x * gridDim.y);
  const int brow = (wg / gridDim.x) * 256;
  const int bcol = (wg % gridDim.x) * 256;

  const int wm = wave >> 2;      // 0..1 -> 128-row half
  const int wn = wave & 3;       // 0..3 -> 64-col slice

  const int rr = tid >> 3;                        // 0..63
  const int cc = (((tid & 7) ^ (rr & 7)) << 3);
  const bf16_t* ga = A  + (size_t)(brow + rr) * K + cc;
  const bf16_t* gb = Bm + (size_t)(bcol + rr) * K + cc;

  auto stA = [&](int d, int i, long ko) {
    load_lds16(ga + (size_t)(i * 64) * K + ko, &As[d][(i * 64 + wave * 8) * 64]);
  };
  auto stB = [&](int d, int i, long ko) {
    load_lds16(gb + (size_t)(i * 64) * K + ko, &Bs[d][(i * 64 + wave * 8) * 64]);
  };

  f32x4 acc[8][4] = {};
  bf16x8 alo[4][2], ahi[4][2], blo[2][2], bhi[2][2];

  const int lr  = lane & 15;
  const int hi  = lane >> 4;
  const int rsw = lr & 7;
  const int arb = wm * 128 + lr;
  const int bcb = wn * 64 + lr;

#define RD_A(DST, MB, dd)                                                     \
  _Pragma("unroll") for (int mf = 0; mf < 4; ++mf)                            \
  _Pragma("unroll") for (int kk = 0; kk < 2; ++kk)                            \
    DST[mf][kk] = *(const bf16x8*)&As[dd][(arb + (MB) * 64 + mf * 16) * 64 +  \
                                          (((kk * 4 + hi) ^ rsw) << 3)];
#define RD_B(DST, NB, dd)                                                     \
  _Pragma("unroll") for (int nf = 0; nf < 2; ++nf)                            \
  _Pragma("unroll") for (int kk = 0; kk < 2; ++kk)                            \
    DST[nf][kk] = *(const bf16x8*)&Bs[dd][(bcb + (NB) * 16 + nf * 16) * 64 +  \
                                          (((kk * 4 + hi) ^ rsw) << 3)];
#define MFMA_Q(AF, BF, MB, NB)                                                \
  _Pragma("unroll") for (int kk = 0; kk < 2; ++kk)                            \
  _Pragma("unroll") for (int mf = 0; mf < 4; ++mf)                            \
  _Pragma("unroll") for (int nf = 0; nf < 2; ++nf)                            \
    acc[(MB) + mf][(NB) + nf] = __builtin_amdgcn_mfma_f32_16x16x32_bf16(      \
        AF[mf][kk], BF[nf][kk], acc[(MB) + mf][(NB) + nf], 0, 0, 0);

#define LGKM0  asm volatile("s_waitcnt lgkmcnt(0)" ::: "memory")
#define LGKM8  asm volatile("s_waitcnt lgkmcnt(8)" ::: "memory")
#define VMW(N) asm volatile("s_waitcnt vmcnt(" #N ")" ::: "memory")
#define BARR   __builtin_amdgcn_s_barrier()
#define PRIO1  __builtin_amdgcn_s_setprio(1)
#define PRIO0  __builtin_amdgcn_s_setprio(0)

  const int NT = K >> 6;          // even by construction

  stA(0, 0, 0); stA(0, 1, 0); stA(0, 2, 0); stA(0, 3, 0);
  stB(0, 0, 0); stB(0, 1, 0); stB(0, 2, 0); stB(0, 3, 0);
  stB(1, 0, 64); stB(1, 1, 64); stB(1, 2, 64); stB(1, 3, 64);
  stA(1, 0, 64); stA(1, 1, 64); stA(1, 2, 64); stA(1, 3, 64);
  VMW(8);
  BARR;

  for (int it = 0; it < (NT >> 1); ++it) {
    const int  T   = it * 2;
    const long k2  = (long)(T + 2) * 64;
    const long k3  = (long)(T + 3) * 64;
    const bool pf2 = (T + 2 < NT);

    RD_A(alo, 0, 0); RD_B(blo, 0, 0);
    LGKM8;
    BARR; LGKM0; PRIO1; MFMA_Q(alo, blo, 0, 0); PRIO0; BARR;

    RD_B(bhi, 2, 0);
    BARR; LGKM0; PRIO1; MFMA_Q(alo, bhi, 0, 2); PRIO0; BARR;

    RD_A(ahi, 1, 0);
    if (pf2) { stB(0, 0, k2); stB(0, 1, k2); }
    BARR; LGKM0; PRIO1; MFMA_Q(ahi, bhi, 4, 2); PRIO0; BARR;

    if (pf2) { stB(0, 2, k2); stB(0, 3, k2); }
    PRIO1; MFMA_Q(ahi, blo, 4, 0); PRIO0;
    if (pf2) { VMW(4); } else { VMW(0); }
    BARR;

    RD_A(alo, 0, 1); RD_B(blo, 0, 1);
    if (pf2) { stA(0, 0, k2); stA(0, 2, k2); }
    LGKM8;
    BARR; LGKM0; PRIO1; MFMA_Q(alo, blo, 0, 0); PRIO0; BARR;

    RD_B(bhi, 2, 1);
    if (pf2) { stA(0, 1, k2); stA(0, 3, k2); }
    BARR; LGKM0; PRIO1; MFMA_Q(alo, bhi, 0, 2); PRIO0; BARR;

    RD_A(ahi, 1, 1);
    if (pf2) { stB(1, 0, k3); stB(1, 1, k3); }
    BARR; LGKM0; PRIO1; MFMA_Q(ahi, bhi, 4, 2); PRIO0; BARR;

    if (pf2) { stB(1, 2, k3); stB(1, 3, k3);
               stA(1, 0, k3); stA(1, 1, k3); stA(1, 2, k3); stA(1, 3, k3); }
    PRIO1; MFMA_Q(ahi, blo, 4, 0); PRIO0;
    if (pf2) { VMW(8); BARR; }
  }

  if (MODE == 0) {
#pragma unroll
    for (int nf = 0; nf < 4; ++nf) {
      const int colg = bcol + wn * 64 + nf * 16 + lr;
      float s = 0.f, s2 = 0.f;
#pragma unroll
      for (int mf = 0; mf < 8; ++mf) {
        const int rowg = brow + wm * 128 + mf * 16 + hi * 4;
#pragma unroll
        for (int r = 0; r < 4; ++r) {
          float v = acc[mf][nf][r];
          s += v; s2 += v * v;
          Cb[(size_t)(rowg + r) * Npad + colg] = (bf16_t)v;
        }
      }
      s  += __shfl_xor(s, 16, 64);  s  += __shfl_xor(s, 32, 64);
      s2 += __shfl_xor(s2, 16, 64); s2 += __shfl_xor(s2, 32, 64);
      if (lane < 16) {
        atomicAdd(&sum[colg], s);
        atomicAdd(&sq[colg], s2);
      }
    }
  } else {
#pragma unroll
    for (int nf = 0; nf < 4; ++nf) {
      const int colg = bcol + wn * 64 + nf * 16 + lr;
      if (colg < Nvalid) {
#pragma unroll
        for (int mf = 0; mf < 8; ++mf) {
          const int rowg = brow + wm * 128 + mf * 16 + hi * 4;
#pragma unroll
          for (int r = 0; r < 4; ++r)
            Cf[(size_t)(rowg + r) * Cld + colg] = acc[mf][nf][r];
        }
      }
    }
  }
#undef RD_A
#undef RD_B
#undef MFMA_Q
#undef LGKM0
#undef LGKM8
#undef VMW
#undef BARR
#undef PRIO1
#undef PRIO0
}

// =======================================================================
// 128x128 4-wave GEMM (round-2 structure) — merger tail
// =======================================================================
template<int MODE>
__global__ __launch_bounds__(256, 2)
void gemm_bt(const bf16_t* __restrict__ A, const bf16_t* __restrict__ Bm,
             int K, bf16_t* __restrict__ Cb, int Npad,
             float* __restrict__ sum, float* __restrict__ sq,
             float* __restrict__ Cf, int Nvalid, int Cld)
{
  __shared__ bf16_t As[128 * 64];
  __shared__ bf16_t Bs[128 * 64];
  const int tid  = threadIdx.x;
  const int wave = tid >> 6;
  const int lane = tid & 63;

  int wg = xcd_swizzle((int)blockIdx.x + (int)blockIdx.y * gridDim.x,
                       gridDim.x * gridDim.y);
  const int brow = (wg / gridDim.x) * 128;
  const int bcol = (wg % gridDim.x) * 128;

  const int wrow = (wave >> 1) * 64;
  const int wcol = (wave & 1) * 64;

  const int rr  = tid >> 3;
  const int cc  = (((tid & 7) ^ (rr & 7)) << 3);

  const bf16_t* ga[4];
  const bf16_t* gb[4];
#pragma unroll
  for (int i = 0; i < 4; ++i) {
    ga[i] = A  + (size_t)(brow + i * 32 + rr) * K + cc;
    gb[i] = Bm + (size_t)(bcol + i * 32 + rr) * K + cc;
  }
  bf16_t* lab = As + wave * 512;
  bf16_t* lbb = Bs + wave * 512;

  f32x4 acc[4][4] = {};

  const int lr  = lane & 15;
  const int g0  = lane >> 4;
  const int rsw = lr & 7;

  for (int kt = 0; kt < K; kt += 64) {
#pragma unroll
    for (int i = 0; i < 4; ++i) {
      load_lds16(ga[i] + kt, lab + i * 2048);
      load_lds16(gb[i] + kt, lbb + i * 2048);
    }
    __syncthreads();
#pragma unroll
    for (int kk = 0; kk < 2; ++kk) {
      const int swz = (((kk * 4 + g0) ^ rsw) << 3);
      bf16x8 af[4], bfr[4];
#pragma unroll
      for (int mi = 0; mi < 4; ++mi)
        af[mi] = *(const bf16x8*)(As + (wrow + mi * 16 + lr) * 64 + swz);
#pragma unroll
      for (int ni = 0; ni < 4; ++ni)
        bfr[ni] = *(const bf16x8*)(Bs + (wcol + ni * 16 + lr) * 64 + swz);
#pragma unroll
      for (int mi = 0; mi < 4; ++mi)
#pragma unroll
        for (int ni = 0; ni < 4; ++ni)
          acc[mi][ni] = __builtin_amdgcn_mfma_f32_16x16x32_bf16(af[mi], bfr[ni], acc[mi][ni], 0, 0, 0);
    }
    __syncthreads();
  }

  const int lcol = lane & 15;
  const int lrow = (lane >> 4) * 4;
  if (MODE == 0) {
#pragma unroll
    for (int ni = 0; ni < 4; ++ni) {
      const int colg = bcol + wcol + ni * 16 + lcol;
      float s = 0.f, s2 = 0.f;
#pragma unroll
      for (int mi = 0; mi < 4; ++mi) {
        const int rowg = brow + wrow + mi * 16 + lrow;
#pragma unroll
        for (int r = 0; r < 4; ++r) {
          float v = acc[mi][ni][r];
          s += v; s2 += v * v;
          Cb[(size_t)(rowg + r) * Npad + colg] = (bf16_t)v;
        }
      }
      s  += __shfl_xor(s, 16, 64);  s  += __shfl_xor(s, 32, 64);
      s2 += __shfl_xor(s2, 16, 64); s2 += __shfl_xor(s2, 32, 64);
      if (lane < 16) {
        atomicAdd(&sum[colg], s);
        atomicAdd(&sq[colg], s2);
      }
    }
  } else {
#pragma unroll
    for (int ni = 0; ni < 4; ++ni) {
      const int colg = bcol + wcol + ni * 16 + lcol;
      if (colg < Nvalid) {
#pragma unroll
        for (int mi = 0; mi < 4; ++mi) {
          const int rowg = brow + wrow + mi * 16 + lrow;
#pragma unroll
          for (int r = 0; r < 4; ++r)
            Cf[(size_t)(rowg + r) * Cld + colg] = acc[mi][ni][r];
        }
      }
    }
  }
}

// =======================================================================
// gemm_tail: K-split 128-col strip for GEMM1 aux columns (4096..4223).
// grid (KS=4 K-slices, 64 row-blocks); block: 128 rows x 128 cols x K=1280.
// Writes f32 partials Pf[ks][8192][128] (no atomics; summed by k_auxfin).
// =======================================================================
__global__ __launch_bounds__(256, 2)
void gemm_tail(const bf16_t* __restrict__ A, const bf16_t* __restrict__ Bm,
               float* __restrict__ Pf)
{
  __shared__ bf16_t As[128 * 64];
  __shared__ bf16_t Bs[128 * 64];
  const int tid  = threadIdx.x;
  const int wave = tid >> 6;
  const int lane = tid & 63;
  const int ksl  = blockIdx.x;               // 0..3
  const int brow = blockIdx.y * 128;
  const long kb  = (long)ksl * 1280;

  const int wrow = (wave >> 1) * 64;
  const int wcol = (wave & 1) * 64;

  const int rr  = tid >> 3;
  const int cc  = (((tid & 7) ^ (rr & 7)) << 3);

  const bf16_t* ga[4];
  const bf16_t* gb[4];
#pragma unroll
  for (int i = 0; i < 4; ++i) {
    ga[i] = A  + (size_t)(brow + i * 32 + rr) * GENP + kb + cc;
    gb[i] = Bm + (size_t)(i * 32 + rr) * GENP + kb + cc;
  }
  bf16_t* lab = As + wave * 512;
  bf16_t* lbb = Bs + wave * 512;

  f32x4 acc[4][4] = {};

  const int lr  = lane & 15;
  const int g0  = lane >> 4;
  const int rsw = lr & 7;

  for (int kt = 0; kt < 1280; kt += 64) {
#pragma unroll
    for (int i = 0; i < 4; ++i) {
      load_lds16(ga[i] + kt, lab + i * 2048);
      load_lds16(gb[i] + kt, lbb + i * 2048);
    }
    __syncthreads();
#pragma unroll
    for (int kk = 0; kk < 2; ++kk) {
      const int swz = (((kk * 4 + g0) ^ rsw) << 3);
      bf16x8 af[4], bfr[4];
#pragma unroll
      for (int mi = 0; mi < 4; ++mi)
        af[mi] = *(const bf16x8*)(As + (wrow + mi * 16 + lr) * 64 + swz);
#pragma unroll
      for (int ni = 0; ni < 4; ++ni)
        bfr[ni] = *(const bf16x8*)(Bs + (wcol + ni * 16 + lr) * 64 + swz);
#pragma unroll
      for (int mi = 0; mi < 4; ++mi)
#pragma unroll
        for (int ni = 0; ni < 4; ++ni)
          acc[mi][ni] = __builtin_amdgcn_mfma_f32_16x16x32_bf16(af[mi], bfr[ni], acc[mi][ni], 0, 0, 0);
    }
    __syncthreads();
  }

  const int lcol = lane & 15;
  const int lrow = (lane >> 4) * 4;
  float* p = Pf + (size_t)ksl * B_ROWS * 128;
#pragma unroll
  for (int ni = 0; ni < 4; ++ni) {
    const int colg = wcol + ni * 16 + lcol;
#pragma unroll
    for (int mi = 0; mi < 4; ++mi) {
      const int rowg = brow + wrow + mi * 16 + lrow;
#pragma unroll
      for (int r = 0; r < 4; ++r)
        p[(size_t)(rowg + r) * 128 + colg] = acc[mi][ni][r];
    }
  }
}

// k_auxfin: hpre[:,4096+c] = sum_ks Pf[ks][:][c] (bf16) + stats for c<32
__global__ __launch_bounds__(256)
void k_auxfin(const float* __restrict__ Pf, bf16_t* __restrict__ hpre,
              float* __restrict__ s1, float* __restrict__ q1)
{
  __shared__ float sb[256], qb[256];
  const int rc  = blockIdx.x;          // 128 chunks of 64 rows
  const int t   = threadIdx.x;
  const int col = t & 127;
  const int half = t >> 7;
  const size_t S = (size_t)B_ROWS * 128;
  float s = 0.f, q = 0.f;
  for (int r2 = 0; r2 < 64; r2 += 2) {
    const int row = rc * 64 + r2 + half;
    const size_t o = (size_t)row * 128 + col;
    float v = Pf[o] + Pf[S + o] + Pf[2 * S + o] + Pf[3 * S + o];
    hpre[(size_t)row * H1P + 4096 + col] = (bf16_t)v;
    s += v; q += v * v;
  }
  sb[t] = s; qb[t] = q;
  __syncthreads();
  if (t < 32) {                        // cols 4096..4127 are the real aux cols
    atomicAdd(&s1[4096 + t], sb[t] + sb[t + 128]);
    atomicAdd(&q1[4096 + t], qb[t] + qb[t + 128]);
  }
}

// ---------------- prep: out[npad][kpad] = bf16(W*mask), zero-padded ----------------
__global__ void k_prep(const float* __restrict__ W, const float* __restrict__ Mk,
                       bf16_t* __restrict__ out, int N, int K, int Npad, int Kpad)
{
  const int  kg    = Kpad >> 3;
  const long total = (long)Npad * kg;
  for (long idx = (long)blockIdx.x * blockDim.x + threadIdx.x; idx < total;
       idx += (long)gridDim.x * blockDim.x) {
    const int n = (int)(idx / kg);
    const int c = (int)(idx % kg) * 8;
    bf16x8 o;
#pragma unroll
    for (int j = 0; j < 8; ++j) o[j] = (bf16_t)0.f;
    if (n < N && c < K) {
      const f32x4* w4 = (const f32x4*)(W + (size_t)n * K + c);
      f32x4 a = w4[0], b = w4[1];
      if (Mk) {
        const f32x4* m4 = (const f32x4*)(Mk + (size_t)n * K + c);
        f32x4 ma = m4[0], mb = m4[1];
        a *= ma; b *= mb;
      }
#pragma unroll
      for (int j = 0; j < 4; ++j) { o[j] = (bf16_t)a[j]; o[4 + j] = (bf16_t)b[j]; }
    }
    *(bf16x8*)(out + (size_t)idx * 8) = o;
  }
}

// ---------------- BN finalize: sum->scale, sq->shift ----------------
__global__ void k_finalize(float* __restrict__ sum, float* __restrict__ sq,
                           const float* __restrict__ g, const float* __restrict__ be,
                           int Nvalid, int Npad)
{
  const int c = blockIdx.x * blockDim.x + threadIdx.x;
  if (c >= Npad) return;
  float sc = 0.f, sh = 0.f;
  if (c < Nvalid) {
    const float invM = 1.0f / 8192.0f;
    float mean = sum[c] * invM;
    float var  = sq[c] * invM - mean * mean;
    sc = g[c] * rsqrtf(var + 1e-3f);
    sh = be[c] - mean * sc;
  }
  sum[c] = sc; sq[c] = sh;
}

// ---------------- BN apply (+optional ELU, optional f32 out) ----------------
__global__ void k_bn_elu(const bf16_t* __restrict__ pre, const float* __restrict__ sc,
                         const float* __restrict__ sh, bf16_t* __restrict__ outb,
                         float* __restrict__ outf, int Nvalid, int Npad, int elu)
{
  const int  ng    = Npad >> 3;
  const long total = (long)B_ROWS * ng;
  for (long idx = (long)blockIdx.x * blockDim.x + threadIdx.x; idx < total;
       idx += (long)gridDim.x * blockDim.x) {
    const int r = (int)(idx / ng);
    const int c = (int)(idx % ng) * 8;
    bf16x8 o;
#pragma unroll
    for (int j = 0; j < 8; ++j) o[j] = (bf16_t)0.f;
    if (c < Nvalid) {
      bf16x8 x = *(const bf16x8*)(pre + (size_t)r * Npad + c);
      f32x4 y0, y1;
#pragma unroll
      for (int j = 0; j < 8; ++j) {
        float v = (float)x[j] * sc[c + j] + sh[c + j];
        if (elu) v = v > 0.f ? v : expm1f(v);
        if (j < 4) y0[j] = v; else y1[j - 4] = v;
        o[j] = (bf16_t)v;
      }
      if (outf) {
        float* p = outf + (size_t)r * Nvalid + c;
        *(f32x4*)p       = y0;
        *(f32x4*)(p + 4) = y1;
      }
    }
    *(bf16x8*)(outb + (size_t)r * Npad + c) = o;
  }
}

// =======================================================================
// k_enc2: block-diagonal encoder L2, fused BN1+ELU (round-6, verified)
// =======================================================================
__global__ __launch_bounds__(256)
void k_enc2(const bf16_t* __restrict__ hpre,
            const float* __restrict__ sc1, const float* __restrict__ sh1,
            const float* __restrict__ W2,
            bf16_t* __restrict__ pp,
            float* __restrict__ s2, float* __restrict__ q2)
{
  __shared__ float ws2[16][32];
  __shared__ float lsc[32], lsh[32];
  __shared__ float dbuf[256][17];
  __shared__ float part[2][4][16];
  const int m = blockIdx.x;
  const int t = threadIdx.x;
  const int b = blockIdx.y * 256 + t;

  for (int i = t; i < 512; i += 256) {
    const int r = i >> 5, j = i & 31;
    const int grow = (r < 8) ? (m * 8 + r) : (LT + m * 8 + (r - 8));
    ws2[r][j] = W2[(size_t)grow * H1 + m * 32 + j];
  }
  if (t < 32) lsc[t] = sc1[m * 32 + t];
  else if (t < 64) lsh[t - 32] = sh1[m * 32 + (t - 32)];
  __syncthreads();

  float h[32];
  const bf16_t* hp = hpre + (size_t)b * H1P + m * 32;
#pragma unroll
  for (int v = 0; v < 4; ++v) {
    bf16x8 x = *(const bf16x8*)(hp + v * 8);
#pragma unroll
    for (int j = 0; j < 8; ++j) {
      float val = (float)x[j] * lsc[v * 8 + j] + lsh[v * 8 + j];
      h[v * 8 + j] = val > 0.f ? val : expm1f(val);
    }
  }

  float p[16];
#pragma unroll
  for (int i = 0; i < 16; ++i) {
    float a = 0.f;
#pragma unroll
    for (int jb = 0; jb < 8; ++jb) {
      f32x4 w = *(const f32x4*)&ws2[i][jb * 4];
      a = fmaf(w[0], h[jb * 4 + 0], a);
      a = fmaf(w[1], h[jb * 4 + 1], a);
      a = fmaf(w[2], h[jb * 4 + 2], a);
      a = fmaf(w[3], h[jb * 4 + 3], a);
    }
    p[i] = a;
  }

  bf16x8 o0, o1;
#pragma unroll
  for (int i = 0; i < 8; ++i) { o0[i] = (bf16_t)p[i]; o1[i] = (bf16_t)p[8 + i]; }
  bf16_t* pw = pp + ((size_t)m * B_ROWS + b) * 16;
  *(bf16x8*)pw = o0; *(bf16x8*)(pw + 8) = o1;

#pragma unroll
  for (int i = 0; i < 16; ++i) dbuf[t][i] = p[i];
  __syncthreads();
  {
    const int col = t & 15, sl = t >> 4;
    float s = 0.f, q = 0.f;
#pragma unroll
    for (int r = 0; r < 16; ++r) {
      float v = dbuf[sl * 16 + r][col];
      s += v; q += v * v;
    }
    s += __shfl_xor(s, 16, 64); s += __shfl_xor(s, 32, 64);
    q += __shfl_xor(q, 16, 64); q += __shfl_xor(q, 32, 64);
    const int w = t >> 6;
    if ((t & 63) < 16) { part[0][w][col] = s; part[1][w][col] = q; }
    __syncthreads();
    if (t < 16) {
      float ss = part[0][0][t] + part[0][1][t] + part[0][2][t] + part[0][3][t];
      float qq = part[1][0][t] + part[1][1][t] + part[1][2][t] + part[1][3][t];
      const int gc = (t < 8) ? (m * 8 + t) : (LT + m * 8 + (t - 8));
      atomicAdd(&s2[gc], ss);
      atomicAdd(&q2[gc], qq);
    }
  }
}

// =======================================================================
// k_dec: fused BN2 + reparametrize + block-diagonal decoder L1 (round-6)
// =======================================================================
__global__ __launch_bounds__(256)
void k_dec(const bf16_t* __restrict__ pp,
           const float* __restrict__ sc2, const float* __restrict__ sh2,
           const float* __restrict__ eps, const float* __restrict__ Wd,
           float* __restrict__ o_z, float* __restrict__ o_mu, float* __restrict__ o_lv,
           bf16_t* __restrict__ dpre,
           float* __restrict__ sd, float* __restrict__ qd)
{
  __shared__ float wd[32][8];
  __shared__ float lsc[16], lsh[16];
  __shared__ float dbuf[256][33];
  __shared__ float part[2][4][32];
  const int m = blockIdx.x;
  const int t = threadIdx.x;
  const int b = blockIdx.y * 256 + t;

  {
    const int j = t >> 3, l = t & 7;
    wd[j][l] = Wd[(size_t)(m * 32 + j) * LT + m * 8 + l];
  }
  if (t < 16) {
    const int gc = (t < 8) ? (m * 8 + t) : (LT + m * 8 + (t - 8));
    lsc[t] = sc2[gc]; lsh[t] = sh2[gc];
  }
  __syncthreads();

  const bf16_t* pr = pp + ((size_t)m * B_ROWS + b) * 16;
  bf16x8 pmv = *(const bf16x8*)pr;
  bf16x8 plv = *(const bf16x8*)(pr + 8);
  f32x4 e0 = *(const f32x4*)(eps + (size_t)b * LT + m * 8);
  f32x4 e1 = *(const f32x4*)(eps + (size_t)b * LT + m * 8 + 4);

  float z[8];
  f32x4 mu0, mu1, lv0, lv1, z0, z1;
#pragma unroll
  for (int l = 0; l < 8; ++l) {
    float muv = (float)pmv[l] * lsc[l] + lsh[l];
    float lvv = (float)plv[l] * lsc[8 + l] + lsh[8 + l];
    float ee  = (l < 4) ? e0[l] : e1[l - 4];
    float zz  = fmaf(expf(lvv * 0.5f), ee, muv);
    z[l] = zz;
    if (l < 4) { mu0[l] = muv; lv0[l] = lvv; z0[l] = zz; }
    else       { mu1[l-4] = muv; lv1[l-4] = lvv; z1[l-4] = zz; }
  }
  {
    const size_t o = (size_t)b * LT + m * 8;
    *(f32x4*)(o_z  + o) = z0; *(f32x4*)(o_z  + o + 4) = z1;
    *(f32x4*)(o_mu + o) = mu0; *(f32x4*)(o_mu + o + 4) = mu1;
    *(f32x4*)(o_lv + o) = lv0; *(f32x4*)(o_lv + o + 4) = lv1;
  }

  float d[32];
#pragma unroll
  for (int j = 0; j < 32; ++j) {
    f32x4 w0 = *(const f32x4*)&wd[j][0];
    f32x4 w1 = *(const f32x4*)&wd[j][4];
    float a = 0.f;
    a = fmaf(w0[0], z[0], a); a = fmaf(w0[1], z[1], a);
    a = fmaf(w0[2], z[2], a); a = fmaf(w0[3], z[3], a);
    a = fmaf(w1[0], z[4], a); a = fmaf(w1[1], z[5], a);
    a = fmaf(w1[2], z[6], a); a = fmaf(w1[3], z[7], a);
    d[j] = a;
  }
  {
    bf16_t* dw = dpre + (size_t)b * H1P + m * 32;
#pragma unroll
    for (int v = 0; v < 4; ++v) {
      bf16x8 o;
#pragma unroll
      for (int j = 0; j < 8; ++j) o[j] = (bf16_t)d[v * 8 + j];
      *(bf16x8*)(dw + v * 8) = o;
    }
  }

#pragma unroll
  for (int j = 0; j < 32; ++j) dbuf[t][j] = d[j];
  __syncthreads();
  {
    const int col = t & 31, sl = t >> 5;
    float s = 0.f, q = 0.f;
#pragma unroll
    for (int r = 0; r < 32; ++r) {
      float v = dbuf[sl * 32 + r][col];
      s += v; q += v * v;
    }
    s += __shfl_xor(s, 32, 64);
    q += __shfl_xor(q, 32, 64);
    const int w = t >> 6;
    if ((t & 63) < 32) { part[0][w][col] = s; part[1][w][col] = q; }
    __syncthreads();
    if (t < 32) {
      float ss = part[0][0][t] + part[0][1][t] + part[0][2][t] + part[0][3][t];
      float qq = part[1][0][t] + part[1][1][t] + part[1][2][t] + part[1][3][t];
      atomicAdd(&sd[m * 32 + t], ss);
      atomicAdd(&qd[m * 32 + t], qq);
    }
  }
}

// ---------------- host ----------------
extern "C" void kernel_launch(void* const* d_in, const int* in_sizes, int n_in,
                              void* d_out, int out_size, void* d_ws, size_t ws_size,
                              hipStream_t stream)
{
  const float* x     = (const float*)d_in[0];
  const float* eps   = (const float*)d_in[1];
  const float* mask1 = (const float*)d_in[2];
  const float* maskm = (const float*)d_in[5];
  const float* W1    = (const float*)d_in[6];
  const float* g1    = (const float*)d_in[8];
  const float* be1   = (const float*)d_in[9];
  const float* W2    = (const float*)d_in[10];
  const float* g2    = (const float*)d_in[12];
  const float* be2   = (const float*)d_in[13];
  const float* Wd    = (const float*)d_in[14];
  const float* gd    = (const float*)d_in[16];
  const float* bed   = (const float*)d_in[17];
  const float* Wm    = (const float*)d_in[18];
  float* out = (float*)d_out;
  char*  ws  = (char*)d_ws;

  size_t off = 0;
  auto alloc = [&](size_t bytes) { size_t o = off; off += (bytes + 255) & ~(size_t)255; return o; };
  const size_t XBF  = alloc((size_t)B_ROWS * GENP * 2);   // x bf16; later mo bf16
  const size_t W1M  = alloc((size_t)H1P * GENP * 2);      // W1 masked; later pp
  const size_t WMM  = alloc((size_t)GENP * H1P * 2);      // Wm masked
  const size_t HPRE = alloc((size_t)B_ROWS * H1P * 2);    // h_pre; later d_pre
  const size_t PAUX = alloc((size_t)4 * B_ROWS * 128 * sizeof(float));  // 16 MB partials
  const size_t STAT = alloc((size_t)(H1P + H2 + H1P) * 2 * sizeof(float));
  if (ws_size < off) {
    fprintf(stderr, "kernel_launch: workspace too small: need %zu have %zu\n", off, ws_size);
    return;
  }

  bf16_t* xb   = (bf16_t*)(ws + XBF);
  bf16_t* w1m  = (bf16_t*)(ws + W1M);
  bf16_t* wmm  = (bf16_t*)(ws + WMM);
  bf16_t* hpre = (bf16_t*)(ws + HPRE);
  float*  paux = (float*)(ws + PAUX);
  bf16_t* pp   = (bf16_t*)(ws + W1M);   // alias: W1 masked dead after GEMM1
  bf16_t* dpre = (bf16_t*)(ws + HPRE);  // alias: h_pre dead after k_enc2
  bf16_t* mobf = (bf16_t*)(ws + XBF);   // alias: x bf16 dead after GEMM1

  float* s1 = (float*)(ws + STAT);
  float* q1 = s1 + H1P;
  float* s2 = q1 + H1P;
  float* q2 = s2 + H2;
  float* sd = q2 + H2;
  float* qd = sd + H1P;

  float* o_recon = out;
  float* o_z     = o_recon + (size_t)B_ROWS * GEN;
  float* o_mo    = o_z     + (size_t)B_ROWS * LT;
  float* o_mu    = o_mo    + (size_t)B_ROWS * H1;
  float* o_lv    = o_mu    + (size_t)B_ROWS * LT;

  hipMemsetAsync(ws + STAT, 0, (size_t)(H1P + H2 + H1P) * 2 * sizeof(float), stream);

  // prep: cast/mask to bf16, zero-padded
  k_prep<<<2048, 256, 0, stream>>>(x,  nullptr, xb,  B_ROWS, GEN, B_ROWS, GENP);
  k_prep<<<2048, 256, 0, stream>>>(W1, mask1,   w1m, H1,  GEN, H1P,  GENP);
  k_prep<<<2048, 256, 0, stream>>>(Wm, maskm,   wmm, GEN, H1,  GENP, H1P);

  // encoder L1: h_pre = x @ W1m^T (+ batch stats)
  // main: cols 0..4095 (modules 0..127) via 256^2 8-phase (512 blocks)
  gemm256<0><<<dim3(4096 / 256, B_ROWS / 256), 512, 0, stream>>>(
      xb, w1m, GENP, hpre, H1P, s1, q1, nullptr, 0, 0);
  // aux module cols 4096..4223: K-split partials (256 blocks) + reduce
  gemm_tail<<<dim3(4, B_ROWS / 128), 256, 0, stream>>>(
      xb, w1m + (size_t)4096 * GENP, paux);
  k_auxfin<<<128, 256, 0, stream>>>(paux, hpre, s1, q1);
  k_finalize<<<(H1P + 255) / 256, 256, 0, stream>>>(s1, q1, g1, be1, H1, H1P);

  // encoder L2 (block-diagonal, fused BN1+ELU) -> pp + stats2
  k_enc2<<<dim3(NMOD, B_ROWS / 256), 256, 0, stream>>>(hpre, s1, q1, W2, pp, s2, q2);
  k_finalize<<<(H2 + 255) / 256, 256, 0, stream>>>(s2, q2, g2, be2, H2, H2);

  // decoder L1 (block-diagonal, fused BN2 + reparam) -> dpre + stats_d + z/mu/lv
  k_dec<<<dim3(NMOD, B_ROWS / 256), 256, 0, stream>>>(pp, s2, q2, eps, Wd,
                                                      o_z, o_mu, o_lv, dpre, sd, qd);
  k_finalize<<<(H1P + 255) / 256, 256, 0, stream>>>(sd, qd, gd, bed, H1, H1P);

  // BN_d + ELU -> module_outputs (bf16 padded + f32 out)
  k_bn_elu<<<2048, 256, 0, stream>>>(dpre, sd, qd, mobf, o_mo, H1, H1P, 1);

  // merger: global_recon = mo @ Wmm^T (f32 out)
  gemm256<1><<<dim3(4096 / 256, B_ROWS / 256), 512, 0, stream>>>(
      mobf, wmm, H1P, nullptr, 0, nullptr, nullptr, o_recon, GEN, GEN);
  gemm_bt<1><<<dim3((GENP - 4096) / 128, B_ROWS / 128), 256, 0, stream>>>(
      mobf, wmm + (size_t)4096 * H1P, H1P, nullptr, 0, nullptr, nullptr,
      o_recon + 4096, GEN - 4096, GEN);
}

// Round 10
// 1203.395 us; speedup vs baseline: 1.0850x; 1.0326x over previous
//
#include <hip/hip_runtime.h>
#include <cstdio>
#include <cstdint>

typedef __bf16 bf16_t;
typedef __bf16 bf16x8 __attribute__((ext_vector_type(8)));
typedef __bf16 bf16x4 __attribute__((ext_vector_type(4)));
typedef float  f32x4  __attribute__((ext_vector_type(4)));

// problem dims
#define B_ROWS 8192
#define GEN    5000
#define GENP   5120   // padded K for gemm1 / N for merger (mult of 256, 64)
#define H1     4128
#define H1P    4224   // stride of hpre/mobf
#define H2     2064
#define LT     1032
#define NMOD   129    // pathway modules (incl. aux)

// ---------------- async global->LDS helper ----------------
__device__ __forceinline__ void load_lds16(const bf16_t* g, bf16_t* l) {
  __builtin_amdgcn_global_load_lds((__attribute__((address_space(1))) void*)g,
                                   (__attribute__((address_space(3))) void*)l,
                                   16, 0, 0);
}

__device__ __forceinline__ int xcd_swizzle(int wg, int nwg) {
  const int q = nwg >> 3, r8 = nwg & 7;
  const int xcd = wg & 7, sidx = wg >> 3;
  return (xcd < r8 ? xcd * (q + 1) : r8 * (q + 1) + (xcd - r8) * q) + sidx;
}

// =======================================================================
// 256x256 8-wave 8-phase GEMM, counted vmcnt, kk-outer MFMA (r8, ~944 TF)
// MODE 0: bf16 C (ld Npad) + per-column sum/sumsq atomics.
// MODE 1: f32 C, row stride Cld, col bound Nvalid.
// =======================================================================
template<int MODE>
__global__ __launch_bounds__(512, 2)
void gemm256(const bf16_t* __restrict__ A, const bf16_t* __restrict__ Bm,
             int K, bf16_t* __restrict__ Cb, int Npad,
             float* __restrict__ sum, float* __restrict__ sq,
             float* __restrict__ Cf, int Nvalid, int Cld)
{
  __shared__ bf16_t As[2][256 * 64];
  __shared__ bf16_t Bs[2][256 * 64];
  const int tid  = threadIdx.x;
  const int wave = tid >> 6;
  const int lane = tid & 63;

  int wg = xcd_swizzle((int)blockIdx.x + (int)blockIdx.y * gridDim.x,
                       gridDim.x * gridDim.y);
  const int brow = (wg / gridDim.x) * 256;
  const int bcol = (wg % gridDim.x) * 256;

  const int wm = wave >> 2;
  const int wn = wave & 3;

  const int rr = tid >> 3;
  const int cc = (((tid & 7) ^ (rr & 7)) << 3);
  const bf16_t* ga = A  + (size_t)(brow + rr) * K + cc;
  const bf16_t* gb = Bm + (size_t)(bcol + rr) * K + cc;

  auto stA = [&](int d, int i, long ko) {
    load_lds16(ga + (size_t)(i * 64) * K + ko, &As[d][(i * 64 + wave * 8) * 64]);
  };
  auto stB = [&](int d, int i, long ko) {
    load_lds16(gb + (size_t)(i * 64) * K + ko, &Bs[d][(i * 64 + wave * 8) * 64]);
  };

  f32x4 acc[8][4] = {};
  bf16x8 alo[4][2], ahi[4][2], blo[2][2], bhi[2][2];

  const int lr  = lane & 15;
  const int hi  = lane >> 4;
  const int rsw = lr & 7;
  const int arb = wm * 128 + lr;
  const int bcb = wn * 64 + lr;

#define RD_A(DST, MB, dd)                                                     \
  _Pragma("unroll") for (int mf = 0; mf < 4; ++mf)                            \
  _Pragma("unroll") for (int kk = 0; kk < 2; ++kk)                            \
    DST[mf][kk] = *(const bf16x8*)&As[dd][(arb + (MB) * 64 + mf * 16) * 64 +  \
                                          (((kk * 4 + hi) ^ rsw) << 3)];
#define RD_B(DST, NB, dd)                                                     \
  _Pragma("unroll") for (int nf = 0; nf < 2; ++nf)                            \
  _Pragma("unroll") for (int kk = 0; kk < 2; ++kk)                            \
    DST[nf][kk] = *(const bf16x8*)&Bs[dd][(bcb + (NB) * 16 + nf * 16) * 64 +  \
                                          (((kk * 4 + hi) ^ rsw) << 3)];
#define MFMA_Q(AF, BF, MB, NB)                                                \
  _Pragma("unroll") for (int kk = 0; kk < 2; ++kk)                            \
  _Pragma("unroll") for (int mf = 0; mf < 4; ++mf)                            \
  _Pragma("unroll") for (int nf = 0; nf < 2; ++nf)                            \
    acc[(MB) + mf][(NB) + nf] = __builtin_amdgcn_mfma_f32_16x16x32_bf16(      \
        AF[mf][kk], BF[nf][kk], acc[(MB) + mf][(NB) + nf], 0, 0, 0);

#define LGKM0  asm volatile("s_waitcnt lgkmcnt(0)" ::: "memory")
#define LGKM8  asm volatile("s_waitcnt lgkmcnt(8)" ::: "memory")
#define VMW(N) asm volatile("s_waitcnt vmcnt(" #N ")" ::: "memory")
#define BARR   __builtin_amdgcn_s_barrier()
#define PRIO1  __builtin_amdgcn_s_setprio(1)
#define PRIO0  __builtin_amdgcn_s_setprio(0)

  const int NT = K >> 6;

  stA(0, 0, 0); stA(0, 1, 0); stA(0, 2, 0); stA(0, 3, 0);
  stB(0, 0, 0); stB(0, 1, 0); stB(0, 2, 0); stB(0, 3, 0);
  stB(1, 0, 64); stB(1, 1, 64); stB(1, 2, 64); stB(1, 3, 64);
  stA(1, 0, 64); stA(1, 1, 64); stA(1, 2, 64); stA(1, 3, 64);
  VMW(8);
  BARR;

  for (int it = 0; it < (NT >> 1); ++it) {
    const int  T   = it * 2;
    const long k2  = (long)(T + 2) * 64;
    const long k3  = (long)(T + 3) * 64;
    const bool pf2 = (T + 2 < NT);

    RD_A(alo, 0, 0); RD_B(blo, 0, 0);
    LGKM8;
    BARR; LGKM0; PRIO1; MFMA_Q(alo, blo, 0, 0); PRIO0; BARR;

    RD_B(bhi, 2, 0);
    BARR; LGKM0; PRIO1; MFMA_Q(alo, bhi, 0, 2); PRIO0; BARR;

    RD_A(ahi, 1, 0);
    if (pf2) { stB(0, 0, k2); stB(0, 1, k2); }
    BARR; LGKM0; PRIO1; MFMA_Q(ahi, bhi, 4, 2); PRIO0; BARR;

    if (pf2) { stB(0, 2, k2); stB(0, 3, k2); }
    PRIO1; MFMA_Q(ahi, blo, 4, 0); PRIO0;
    if (pf2) { VMW(4); } else { VMW(0); }
    BARR;

    RD_A(alo, 0, 1); RD_B(blo, 0, 1);
    if (pf2) { stA(0, 0, k2); stA(0, 2, k2); }
    LGKM8;
    BARR; LGKM0; PRIO1; MFMA_Q(alo, blo, 0, 0); PRIO0; BARR;

    RD_B(bhi, 2, 1);
    if (pf2) { stA(0, 1, k2); stA(0, 3, k2); }
    BARR; LGKM0; PRIO1; MFMA_Q(alo, bhi, 0, 2); PRIO0; BARR;

    RD_A(ahi, 1, 1);
    if (pf2) { stB(1, 0, k3); stB(1, 1, k3); }
    BARR; LGKM0; PRIO1; MFMA_Q(ahi, bhi, 4, 2); PRIO0; BARR;

    if (pf2) { stB(1, 2, k3); stB(1, 3, k3);
               stA(1, 0, k3); stA(1, 1, k3); stA(1, 2, k3); stA(1, 3, k3); }
    PRIO1; MFMA_Q(ahi, blo, 4, 0); PRIO0;
    if (pf2) { VMW(8); BARR; }
  }

  if (MODE == 0) {
#pragma unroll
    for (int nf = 0; nf < 4; ++nf) {
      const int colg = bcol + wn * 64 + nf * 16 + lr;
      float s = 0.f, s2 = 0.f;
#pragma unroll
      for (int mf = 0; mf < 8; ++mf) {
        const int rowg = brow + wm * 128 + mf * 16 + hi * 4;
#pragma unroll
        for (int r = 0; r < 4; ++r) {
          float v = acc[mf][nf][r];
          s += v; s2 += v * v;
          Cb[(size_t)(rowg + r) * Npad + colg] = (bf16_t)v;
        }
      }
      s  += __shfl_xor(s, 16, 64);  s  += __shfl_xor(s, 32, 64);
      s2 += __shfl_xor(s2, 16, 64); s2 += __shfl_xor(s2, 32, 64);
      if (lane < 16) {
        atomicAdd(&sum[colg], s);
        atomicAdd(&sq[colg], s2);
      }
    }
  } else {
#pragma unroll
    for (int nf = 0; nf < 4; ++nf) {
      const int colg = bcol + wn * 64 + nf * 16 + lr;
      if (colg < Nvalid) {
#pragma unroll
        for (int mf = 0; mf < 8; ++mf) {
          const int rowg = brow + wm * 128 + mf * 16 + hi * 4;
#pragma unroll
          for (int r = 0; r < 4; ++r)
            Cf[(size_t)(rowg + r) * Cld + colg] = acc[mf][nf][r];
        }
      }
    }
  }
#undef RD_A
#undef RD_B
#undef MFMA_Q
#undef LGKM0
#undef LGKM8
#undef VMW
#undef BARR
#undef PRIO1
#undef PRIO0
}

// =======================================================================
// 128x128 4-wave GEMM — merger tail (MODE 1 only used)
// =======================================================================
template<int MODE>
__global__ __launch_bounds__(256, 2)
void gemm_bt(const bf16_t* __restrict__ A, const bf16_t* __restrict__ Bm,
             int K, float* __restrict__ Cf, int Nvalid, int Cld)
{
  __shared__ bf16_t As[128 * 64];
  __shared__ bf16_t Bs[128 * 64];
  const int tid  = threadIdx.x;
  const int wave = tid >> 6;
  const int lane = tid & 63;

  int wg = xcd_swizzle((int)blockIdx.x + (int)blockIdx.y * gridDim.x,
                       gridDim.x * gridDim.y);
  const int brow = (wg / gridDim.x) * 128;
  const int bcol = (wg % gridDim.x) * 128;

  const int wrow = (wave >> 1) * 64;
  const int wcol = (wave & 1) * 64;

  const int rr  = tid >> 3;
  const int cc  = (((tid & 7) ^ (rr & 7)) << 3);

  const bf16_t* ga[4];
  const bf16_t* gb[4];
#pragma unroll
  for (int i = 0; i < 4; ++i) {
    ga[i] = A  + (size_t)(brow + i * 32 + rr) * K + cc;
    gb[i] = Bm + (size_t)(bcol + i * 32 + rr) * K + cc;
  }
  bf16_t* lab = As + wave * 512;
  bf16_t* lbb = Bs + wave * 512;

  f32x4 acc[4][4] = {};

  const int lr  = lane & 15;
  const int g0  = lane >> 4;
  const int rsw = lr & 7;

  for (int kt = 0; kt < K; kt += 64) {
#pragma unroll
    for (int i = 0; i < 4; ++i) {
      load_lds16(ga[i] + kt, lab + i * 2048);
      load_lds16(gb[i] + kt, lbb + i * 2048);
    }
    __syncthreads();
#pragma unroll
    for (int kk = 0; kk < 2; ++kk) {
      const int swz = (((kk * 4 + g0) ^ rsw) << 3);
      bf16x8 af[4], bfr[4];
#pragma unroll
      for (int mi = 0; mi < 4; ++mi)
        af[mi] = *(const bf16x8*)(As + (wrow + mi * 16 + lr) * 64 + swz);
#pragma unroll
      for (int ni = 0; ni < 4; ++ni)
        bfr[ni] = *(const bf16x8*)(Bs + (wcol + ni * 16 + lr) * 64 + swz);
#pragma unroll
      for (int mi = 0; mi < 4; ++mi)
#pragma unroll
        for (int ni = 0; ni < 4; ++ni)
          acc[mi][ni] = __builtin_amdgcn_mfma_f32_16x16x32_bf16(af[mi], bfr[ni], acc[mi][ni], 0, 0, 0);
    }
    __syncthreads();
  }

  const int lcol = lane & 15;
  const int lrow = (lane >> 4) * 4;
#pragma unroll
  for (int ni = 0; ni < 4; ++ni) {
    const int colg = bcol + wcol + ni * 16 + lcol;
    if (colg < Nvalid) {
#pragma unroll
      for (int mi = 0; mi < 4; ++mi) {
        const int rowg = brow + wrow + mi * 16 + lrow;
#pragma unroll
        for (int r = 0; r < 4; ++r)
          Cf[(size_t)(rowg + r) * Cld + colg] = acc[mi][ni][r];
      }
    }
  }
}

// =======================================================================
// gemm_tail: K-split 128-col strip for GEMM1 aux columns (4096..4223).
// grid (4 K-slices, 64 row-blocks); writes f32 partials (no atomics).
// =======================================================================
__global__ __launch_bounds__(256, 2)
void gemm_tail(const bf16_t* __restrict__ A, const bf16_t* __restrict__ Bm,
               float* __restrict__ Pf)
{
  __shared__ bf16_t As[128 * 64];
  __shared__ bf16_t Bs[128 * 64];
  const int tid  = threadIdx.x;
  const int wave = tid >> 6;
  const int lane = tid & 63;
  const int ksl  = blockIdx.x;
  const int brow = blockIdx.y * 128;
  const long kb  = (long)ksl * 1280;

  const int wrow = (wave >> 1) * 64;
  const int wcol = (wave & 1) * 64;

  const int rr  = tid >> 3;
  const int cc  = (((tid & 7) ^ (rr & 7)) << 3);

  const bf16_t* ga[4];
  const bf16_t* gb[4];
#pragma unroll
  for (int i = 0; i < 4; ++i) {
    ga[i] = A  + (size_t)(brow + i * 32 + rr) * GENP + kb + cc;
    gb[i] = Bm + (size_t)(i * 32 + rr) * GENP + kb + cc;
  }
  bf16_t* lab = As + wave * 512;
  bf16_t* lbb = Bs + wave * 512;

  f32x4 acc[4][4] = {};

  const int lr  = lane & 15;
  const int g0  = lane >> 4;
  const int rsw = lr & 7;

  for (int kt = 0; kt < 1280; kt += 64) {
#pragma unroll
    for (int i = 0; i < 4; ++i) {
      load_lds16(ga[i] + kt, lab + i * 2048);
      load_lds16(gb[i] + kt, lbb + i * 2048);
    }
    __syncthreads();
#pragma unroll
    for (int kk = 0; kk < 2; ++kk) {
      const int swz = (((kk * 4 + g0) ^ rsw) << 3);
      bf16x8 af[4], bfr[4];
#pragma unroll
      for (int mi = 0; mi < 4; ++mi)
        af[mi] = *(const bf16x8*)(As + (wrow + mi * 16 + lr) * 64 + swz);
#pragma unroll
      for (int ni = 0; ni < 4; ++ni)
        bfr[ni] = *(const bf16x8*)(Bs + (wcol + ni * 16 + lr) * 64 + swz);
#pragma unroll
      for (int mi = 0; mi < 4; ++mi)
#pragma unroll
        for (int ni = 0; ni < 4; ++ni)
          acc[mi][ni] = __builtin_amdgcn_mfma_f32_16x16x32_bf16(af[mi], bfr[ni], acc[mi][ni], 0, 0, 0);
    }
    __syncthreads();
  }

  const int lcol = lane & 15;
  const int lrow = (lane >> 4) * 4;
  float* p = Pf + (size_t)ksl * B_ROWS * 128;
#pragma unroll
  for (int ni = 0; ni < 4; ++ni) {
    const int colg = wcol + ni * 16 + lcol;
#pragma unroll
    for (int mi = 0; mi < 4; ++mi) {
      const int rowg = brow + wrow + mi * 16 + lrow;
#pragma unroll
      for (int r = 0; r < 4; ++r)
        p[(size_t)(rowg + r) * 128 + colg] = acc[mi][ni][r];
    }
  }
}

// k_auxfin: hpre[:,4096+c] = sum_ks Pf[ks][:][c] (bf16) + stats for c<32
__global__ __launch_bounds__(256)
void k_auxfin(const float* __restrict__ Pf, bf16_t* __restrict__ hpre,
              float* __restrict__ s1, float* __restrict__ q1)
{
  __shared__ float sb[256], qb[256];
  const int rc  = blockIdx.x;
  const int t   = threadIdx.x;
  const int col = t & 127;
  const int half = t >> 7;
  const size_t S = (size_t)B_ROWS * 128;
  float s = 0.f, q = 0.f;
  for (int r2 = 0; r2 < 64; r2 += 2) {
    const int row = rc * 64 + r2 + half;
    const size_t o = (size_t)row * 128 + col;
    float v = Pf[o] + Pf[S + o] + Pf[2 * S + o] + Pf[3 * S + o];
    hpre[(size_t)row * H1P + 4096 + col] = (bf16_t)v;
    s += v; q += v * v;
  }
  sb[t] = s; qb[t] = q;
  __syncthreads();
  if (t < 32) {
    atomicAdd(&s1[4096 + t], sb[t] + sb[t + 128]);
    atomicAdd(&q1[4096 + t], qb[t] + qb[t + 128]);
  }
}

// ---------------- prep (2D grid, no div): out[n][Kpad] = bf16(W*mask) ------
__global__ void k_prep(const float* __restrict__ W, const float* __restrict__ Mk,
                       bf16_t* __restrict__ out, int N, int K, int Kpad)
{
  const int n = blockIdx.y;
  const int c = (blockIdx.x * blockDim.x + threadIdx.x) * 8;
  if (c >= Kpad) return;
  bf16x8 o;
#pragma unroll
  for (int j = 0; j < 8; ++j) o[j] = (bf16_t)0.f;
  if (n < N && c < K) {               // K % 8 == 0 for all inputs
    const f32x4* w4 = (const f32x4*)(W + (size_t)n * K + c);
    f32x4 a = w4[0], b = w4[1];
    if (Mk) {
      const f32x4* m4 = (const f32x4*)(Mk + (size_t)n * K + c);
      a *= m4[0]; b *= m4[1];
    }
#pragma unroll
    for (int j = 0; j < 4; ++j) { o[j] = (bf16_t)a[j]; o[4 + j] = (bf16_t)b[j]; }
  }
  *(bf16x8*)(out + (size_t)n * Kpad + c) = o;
}

// =======================================================================
// k_enc2: block-diagonal encoder L2, fused BN1-finalize + BN1+ELU
// =======================================================================
__global__ __launch_bounds__(256)
void k_enc2(const bf16_t* __restrict__ hpre,
            const float* __restrict__ s1, const float* __restrict__ q1,
            const float* __restrict__ g1, const float* __restrict__ be1,
            const float* __restrict__ W2,
            bf16_t* __restrict__ pp,
            float* __restrict__ s2, float* __restrict__ q2)
{
  __shared__ float ws2[16][32];
  __shared__ float lsc[32], lsh[32];
  __shared__ float dbuf[256][17];
  __shared__ float part[2][4][16];
  const int m = blockIdx.x;
  const int t = threadIdx.x;
  const int b = blockIdx.y * 256 + t;

  for (int i = t; i < 512; i += 256) {
    const int r = i >> 5, j = i & 31;
    const int grow = (r < 8) ? (m * 8 + r) : (LT + m * 8 + (r - 8));
    ws2[r][j] = W2[(size_t)grow * H1 + m * 32 + j];
  }
  if (t < 32) {
    const int gc = m * 32 + t;
    const float invM = 1.0f / 8192.0f;
    float mean = s1[gc] * invM;
    float var  = q1[gc] * invM - mean * mean;
    float sc   = g1[gc] * rsqrtf(var + 1e-3f);
    lsc[t] = sc; lsh[t] = be1[gc] - mean * sc;
  }
  __syncthreads();

  float h[32];
  const bf16_t* hp = hpre + (size_t)b * H1P + m * 32;
#pragma unroll
  for (int v = 0; v < 4; ++v) {
    bf16x8 x = *(const bf16x8*)(hp + v * 8);
#pragma unroll
    for (int j = 0; j < 8; ++j) {
      float val = (float)x[j] * lsc[v * 8 + j] + lsh[v * 8 + j];
      h[v * 8 + j] = val > 0.f ? val : expm1f(val);
    }
  }

  float p[16];
#pragma unroll
  for (int i = 0; i < 16; ++i) {
    float a = 0.f;
#pragma unroll
    for (int jb = 0; jb < 8; ++jb) {
      f32x4 w = *(const f32x4*)&ws2[i][jb * 4];
      a = fmaf(w[0], h[jb * 4 + 0], a);
      a = fmaf(w[1], h[jb * 4 + 1], a);
      a = fmaf(w[2], h[jb * 4 + 2], a);
      a = fmaf(w[3], h[jb * 4 + 3], a);
    }
    p[i] = a;
  }

  bf16x8 o0, o1;
#pragma unroll
  for (int i = 0; i < 8; ++i) { o0[i] = (bf16_t)p[i]; o1[i] = (bf16_t)p[8 + i]; }
  bf16_t* pw = pp + ((size_t)m * B_ROWS + b) * 16;
  *(bf16x8*)pw = o0; *(bf16x8*)(pw + 8) = o1;

#pragma unroll
  for (int i = 0; i < 16; ++i) dbuf[t][i] = p[i];
  __syncthreads();
  {
    const int col = t & 15, sl = t >> 4;
    float s = 0.f, q = 0.f;
#pragma unroll
    for (int r = 0; r < 16; ++r) {
      float v = dbuf[sl * 16 + r][col];
      s += v; q += v * v;
    }
    s += __shfl_xor(s, 16, 64); s += __shfl_xor(s, 32, 64);
    q += __shfl_xor(q, 16, 64); q += __shfl_xor(q, 32, 64);
    const int w = t >> 6;
    if ((t & 63) < 16) { part[0][w][col] = s; part[1][w][col] = q; }
    __syncthreads();
    if (t < 16) {
      float ss = part[0][0][t] + part[0][1][t] + part[0][2][t] + part[0][3][t];
      float qq = part[1][0][t] + part[1][1][t] + part[1][2][t] + part[1][3][t];
      const int gc = (t < 8) ? (m * 8 + t) : (LT + m * 8 + (t - 8));
      atomicAdd(&s2[gc], ss);
      atomicAdd(&q2[gc], qq);
    }
  }
}

// =======================================================================
// k_dec: fused BN2-finalize + reparam + block-diag decoder L1 STATS ONLY
// (d is recomputed from z in k_mo; no dpre materialization)
// =======================================================================
__global__ __launch_bounds__(256)
void k_dec(const bf16_t* __restrict__ pp,
           const float* __restrict__ s2, const float* __restrict__ q2,
           const float* __restrict__ g2, const float* __restrict__ be2,
           const float* __restrict__ eps, const float* __restrict__ Wd,
           float* __restrict__ o_z, float* __restrict__ o_mu, float* __restrict__ o_lv,
           float* __restrict__ sd, float* __restrict__ qd)
{
  __shared__ float wd[32][8];
  __shared__ float lsc[16], lsh[16];
  __shared__ float dbuf[256][33];
  __shared__ float part[2][4][32];
  const int m = blockIdx.x;
  const int t = threadIdx.x;
  const int b = blockIdx.y * 256 + t;

  {
    const int j = t >> 3, l = t & 7;
    wd[j][l] = Wd[(size_t)(m * 32 + j) * LT + m * 8 + l];
  }
  if (t < 16) {
    const int gc = (t < 8) ? (m * 8 + t) : (LT + m * 8 + (t - 8));
    const float invM = 1.0f / 8192.0f;
    float mean = s2[gc] * invM;
    float var  = q2[gc] * invM - mean * mean;
    float sc   = g2[gc] * rsqrtf(var + 1e-3f);
    lsc[t] = sc; lsh[t] = be2[gc] - mean * sc;
  }
  __syncthreads();

  const bf16_t* pr = pp + ((size_t)m * B_ROWS + b) * 16;
  bf16x8 pmv = *(const bf16x8*)pr;
  bf16x8 plv = *(const bf16x8*)(pr + 8);
  f32x4 e0 = *(const f32x4*)(eps + (size_t)b * LT + m * 8);
  f32x4 e1 = *(const f32x4*)(eps + (size_t)b * LT + m * 8 + 4);

  float z[8];
  f32x4 mu0, mu1, lv0, lv1, z0, z1;
#pragma unroll
  for (int l = 0; l < 8; ++l) {
    float muv = (float)pmv[l] * lsc[l] + lsh[l];
    float lvv = (float)plv[l] * lsc[8 + l] + lsh[8 + l];
    float ee  = (l < 4) ? e0[l] : e1[l - 4];
    float zz  = fmaf(expf(lvv * 0.5f), ee, muv);
    z[l] = zz;
    if (l < 4) { mu0[l] = muv; lv0[l] = lvv; z0[l] = zz; }
    else       { mu1[l-4] = muv; lv1[l-4] = lvv; z1[l-4] = zz; }
  }
  {
    const size_t o = (size_t)b * LT + m * 8;
    *(f32x4*)(o_z  + o) = z0; *(f32x4*)(o_z  + o + 4) = z1;
    *(f32x4*)(o_mu + o) = mu0; *(f32x4*)(o_mu + o + 4) = mu1;
    *(f32x4*)(o_lv + o) = lv0; *(f32x4*)(o_lv + o + 4) = lv1;
  }

  float d[32];
#pragma unroll
  for (int j = 0; j < 32; ++j) {
    f32x4 w0 = *(const f32x4*)&wd[j][0];
    f32x4 w1 = *(const f32x4*)&wd[j][4];
    float a = 0.f;
    a = fmaf(w0[0], z[0], a); a = fmaf(w0[1], z[1], a);
    a = fmaf(w0[2], z[2], a); a = fmaf(w0[3], z[3], a);
    a = fmaf(w1[0], z[4], a); a = fmaf(w1[1], z[5], a);
    a = fmaf(w1[2], z[6], a); a = fmaf(w1[3], z[7], a);
    d[j] = a;
  }

#pragma unroll
  for (int j = 0; j < 32; ++j) dbuf[t][j] = d[j];
  __syncthreads();
  {
    const int col = t & 31, sl = t >> 5;
    float s = 0.f, q = 0.f;
#pragma unroll
    for (int r = 0; r < 32; ++r) {
      float v = dbuf[sl * 32 + r][col];
      s += v; q += v * v;
    }
    s += __shfl_xor(s, 32, 64);
    q += __shfl_xor(q, 32, 64);
    const int w = t >> 6;
    if ((t & 63) < 32) { part[0][w][col] = s; part[1][w][col] = q; }
    __syncthreads();
    if (t < 32) {
      float ss = part[0][0][t] + part[0][1][t] + part[0][2][t] + part[0][3][t];
      float qq = part[1][0][t] + part[1][1][t] + part[1][2][t] + part[1][3][t];
      atomicAdd(&sd[m * 32 + t], ss);
      atomicAdd(&qd[m * 32 + t], qq);
    }
  }
}

// =======================================================================
// k_mo: recompute d = z @ Wd_blk, fused BN_d-finalize + BN+ELU ->
// mobf bf16 (stride H1P) + o_mo f32 (stride H1)
// =======================================================================
__global__ __launch_bounds__(256)
void k_mo(const float* __restrict__ z,
          const float* __restrict__ sd, const float* __restrict__ qd,
          const float* __restrict__ gd, const float* __restrict__ bed,
          const float* __restrict__ Wd,
          bf16_t* __restrict__ mobf, float* __restrict__ o_mo)
{
  __shared__ float wd[32][8];
  __shared__ float lsc[32], lsh[32];
  const int m = blockIdx.x;
  const int t = threadIdx.x;
  const int b = blockIdx.y * 256 + t;

  {
    const int j = t >> 3, l = t & 7;
    wd[j][l] = Wd[(size_t)(m * 32 + j) * LT + m * 8 + l];
  }
  if (t < 32) {
    const int gc = m * 32 + t;
    const float invM = 1.0f / 8192.0f;
    float mean = sd[gc] * invM;
    float var  = qd[gc] * invM - mean * mean;
    float sc   = gd[gc] * rsqrtf(var + 1e-3f);
    lsc[t] = sc; lsh[t] = bed[gc] - mean * sc;
  }
  __syncthreads();

  f32x4 za = *(const f32x4*)(z + (size_t)b * LT + m * 8);
  f32x4 zb = *(const f32x4*)(z + (size_t)b * LT + m * 8 + 4);

  bf16_t* mw = mobf + (size_t)b * H1P + m * 32;
  float*  ow = o_mo + (size_t)b * H1  + m * 32;
#pragma unroll
  for (int v = 0; v < 4; ++v) {
    bf16x8 ob;
    f32x4 y0, y1;
#pragma unroll
    for (int jj = 0; jj < 8; ++jj) {
      const int j = v * 8 + jj;
      f32x4 w0 = *(const f32x4*)&wd[j][0];
      f32x4 w1 = *(const f32x4*)&wd[j][4];
      float a = 0.f;
      a = fmaf(w0[0], za[0], a); a = fmaf(w0[1], za[1], a);
      a = fmaf(w0[2], za[2], a); a = fmaf(w0[3], za[3], a);
      a = fmaf(w1[0], zb[0], a); a = fmaf(w1[1], zb[1], a);
      a = fmaf(w1[2], zb[2], a); a = fmaf(w1[3], zb[3], a);
      float val = a * lsc[j] + lsh[j];
      val = val > 0.f ? val : expm1f(val);
      ob[jj] = (bf16_t)val;
      if (jj < 4) y0[jj] = val; else y1[jj - 4] = val;
    }
    *(bf16x8*)(mw + v * 8) = ob;
    *(f32x4*)(ow + v * 8)     = y0;
    *(f32x4*)(ow + v * 8 + 4) = y1;
  }
}

// ---------------- host ----------------
extern "C" void kernel_launch(void* const* d_in, const int* in_sizes, int n_in,
                              void* d_out, int out_size, void* d_ws, size_t ws_size,
                              hipStream_t stream)
{
  const float* x     = (const float*)d_in[0];
  const float* eps   = (const float*)d_in[1];
  const float* mask1 = (const float*)d_in[2];
  const float* maskm = (const float*)d_in[5];
  const float* W1    = (const float*)d_in[6];
  const float* g1    = (const float*)d_in[8];
  const float* be1   = (const float*)d_in[9];
  const float* W2    = (const float*)d_in[10];
  const float* g2    = (const float*)d_in[12];
  const float* be2   = (const float*)d_in[13];
  const float* Wd    = (const float*)d_in[14];
  const float* gd    = (const float*)d_in[16];
  const float* bed   = (const float*)d_in[17];
  const float* Wm    = (const float*)d_in[18];
  float* out = (float*)d_out;
  char*  ws  = (char*)d_ws;

  size_t off = 0;
  auto alloc = [&](size_t bytes) { size_t o = off; off += (bytes + 255) & ~(size_t)255; return o; };
  const size_t XBF  = alloc((size_t)B_ROWS * GENP * 2);   // x bf16; later mobf
  const size_t W1M  = alloc((size_t)H1P * GENP * 2);      // W1 masked; later pp
  const size_t WMM  = alloc((size_t)GENP * H1P * 2);      // Wm masked
  const size_t HPRE = alloc((size_t)B_ROWS * H1P * 2);    // h_pre
  const size_t PAUX = alloc((size_t)4 * B_ROWS * 128 * sizeof(float));
  const size_t STAT = alloc((size_t)(H1P + H2 + H1P) * 2 * sizeof(float));
  if (ws_size < off) {
    fprintf(stderr, "kernel_launch: workspace too small: need %zu have %zu\n", off, ws_size);
    return;
  }

  bf16_t* xb   = (bf16_t*)(ws + XBF);
  bf16_t* w1m  = (bf16_t*)(ws + W1M);
  bf16_t* wmm  = (bf16_t*)(ws + WMM);
  bf16_t* hpre = (bf16_t*)(ws + HPRE);
  float*  paux = (float*)(ws + PAUX);
  bf16_t* pp   = (bf16_t*)(ws + W1M);   // alias: W1 masked dead after GEMM1
  bf16_t* mobf = (bf16_t*)(ws + XBF);   // alias: x bf16 dead after GEMM1(+tail)

  float* s1 = (float*)(ws + STAT);
  float* q1 = s1 + H1P;
  float* s2 = q1 + H1P;
  float* q2 = s2 + H2;
  float* sd = q2 + H2;
  float* qd = sd + H1P;

  float* o_recon = out;
  float* o_z     = o_recon + (size_t)B_ROWS * GEN;
  float* o_mo    = o_z     + (size_t)B_ROWS * LT;
  float* o_mu    = o_mo    + (size_t)B_ROWS * H1;
  float* o_lv    = o_mu    + (size_t)B_ROWS * LT;

  hipMemsetAsync(ws + STAT, 0, (size_t)(H1P + H2 + H1P) * 2 * sizeof(float), stream);

  // prep: cast/mask to bf16, zero-padded (2D grids, no integer div)
  k_prep<<<dim3((GENP / 8 + 255) / 256, B_ROWS), 256, 0, stream>>>(
      x, nullptr, xb, B_ROWS, GEN, GENP);
  k_prep<<<dim3((GENP / 8 + 255) / 256, H1P), 256, 0, stream>>>(
      W1, mask1, w1m, H1, GEN, GENP);
  k_prep<<<dim3((H1P / 8 + 255) / 256, GENP), 256, 0, stream>>>(
      Wm, maskm, wmm, GEN, H1, H1P);

  // encoder L1: h_pre = x @ W1m^T (+ batch stats)
  gemm256<0><<<dim3(4096 / 256, B_ROWS / 256), 512, 0, stream>>>(
      xb, w1m, GENP, hpre, H1P, s1, q1, nullptr, 0, 0);
  gemm_tail<<<dim3(4, B_ROWS / 128), 256, 0, stream>>>(
      xb, w1m + (size_t)4096 * GENP, paux);
  k_auxfin<<<128, 256, 0, stream>>>(paux, hpre, s1, q1);

  // encoder L2 (block-diagonal, fused BN1-finalize+BN1+ELU) -> pp + stats2
  k_enc2<<<dim3(NMOD, B_ROWS / 256), 256, 0, stream>>>(
      hpre, s1, q1, g1, be1, W2, pp, s2, q2);

  // decoder L1 (fused BN2-finalize + reparam + d-stats; no dpre)
  k_dec<<<dim3(NMOD, B_ROWS / 256), 256, 0, stream>>>(
      pp, s2, q2, g2, be2, eps, Wd, o_z, o_mu, o_lv, sd, qd);

  // module outputs: recompute d from z, fused BN_d-finalize + BN+ELU
  k_mo<<<dim3(NMOD, B_ROWS / 256), 256, 0, stream>>>(
      o_z, sd, qd, gd, bed, Wd, mobf, o_mo);

  // merger: global_recon = mo @ Wmm^T (f32 out)
  gemm256<1><<<dim3(4096 / 256, B_ROWS / 256), 512, 0, stream>>>(
      mobf, wmm, H1P, nullptr, 0, nullptr, nullptr, o_recon, GEN, GEN);
  gemm_bt<1><<<dim3((GENP - 4096) / 128, B_ROWS / 128), 256, 0, stream>>>(
      mobf, wmm + (size_t)4096 * H1P, H1P, o_recon + 4096, GEN - 4096, GEN);
}